// Round 1
// baseline (1875.917 us; speedup 1.0000x reference)
//
#include <hip/hip_runtime.h>
#include <math.h>

// Problem constants (from reference): N=25000, E=400000
// S=8, NB=8, RMAX=5, EMB=16, MULS=(8,4,4), DIMS=(1,3,5), feat=40, WNUM=1024

__device__ __forceinline__ float silu_f(float x) {
    return x / (1.0f + __expf(-x));
}

// ---------------- Atom MLP: atom_table[A] -> 16 -> 64 -> 32 -> 8 ----------------
__global__ __launch_bounds__(256) void atoms_kernel(
    const float* __restrict__ atom_table, const int* __restrict__ A,
    const float* __restrict__ fw1, const float* __restrict__ fb1,
    const float* __restrict__ fw2, const float* __restrict__ fb2,
    const float* __restrict__ fw3, const float* __restrict__ fb3,
    float* __restrict__ Ai, int n_atoms)
{
    int n = blockIdx.x * blockDim.x + threadIdx.x;
    if (n >= n_atoms) return;
    int a = A[n];
    const float* at = atom_table + a * 16;

    float h1[64];
#pragma unroll
    for (int t = 0; t < 64; ++t) h1[t] = fb1[t];
#pragma unroll
    for (int k = 0; k < 16; ++k) {
        float x = at[k];
#pragma unroll
        for (int t = 0; t < 64; ++t) h1[t] += x * fw1[k * 64 + t];
    }
#pragma unroll
    for (int t = 0; t < 64; ++t) h1[t] = silu_f(h1[t]);

    float h2[32];
#pragma unroll
    for (int t = 0; t < 32; ++t) h2[t] = fb2[t];
#pragma unroll
    for (int k = 0; k < 64; ++k) {
        float x = h1[k];
#pragma unroll
        for (int t = 0; t < 32; ++t) h2[t] += x * fw2[k * 32 + t];
    }
#pragma unroll
    for (int t = 0; t < 32; ++t) h2[t] = silu_f(h2[t]);

    float o[8];
#pragma unroll
    for (int t = 0; t < 8; ++t) o[t] = fb3[t];
#pragma unroll
    for (int k = 0; k < 32; ++k) {
        float x = h2[k];
#pragma unroll
        for (int t = 0; t < 8; ++t) o[t] += x * fw3[k * 8 + t];
    }
#pragma unroll
    for (int t = 0; t < 8; ++t) Ai[n * 8 + t] = o[t];
}

// ---------------- Edge kernel ----------------
// g[u] accumulation over one gw4 row (wave-uniform address -> scalar loads).
// w layout per edge: block0 [0,512): (i*8+j)*8+u  (mul=8)
//                    block1 [512,768): 512+(i*8+j)*4+u (mul=4)
//                    block2 [768,1024): 768+(i*8+j)*4+u (mul=4)
__device__ __forceinline__ void accum_row(const float* __restrict__ row,
                                          float hk,
                                          const float (&c)[64],
                                          float (&g)[16])
{
    float m[16];
#pragma unroll
    for (int u = 0; u < 16; ++u) m[u] = 0.0f;
#pragma unroll
    for (int p = 0; p < 64; ++p) {
        float cp = c[p];
#pragma unroll
        for (int u = 0; u < 8; ++u)  m[u]      += cp * row[p * 8 + u];
#pragma unroll
        for (int u = 0; u < 4; ++u)  m[8 + u]  += cp * row[512 + p * 4 + u];
#pragma unroll
        for (int u = 0; u < 4; ++u)  m[12 + u] += cp * row[768 + p * 4 + u];
    }
#pragma unroll
    for (int u = 0; u < 16; ++u) g[u] += hk * m[u];
}

#define EBLK 128

__global__ __launch_bounds__(EBLK, 2) void edge_kernel(
    const float* __restrict__ pos, const float* __restrict__ edge_shifts,
    const float* __restrict__ cell, const int* __restrict__ batch,
    const int* __restrict__ edge_src, const int* __restrict__ edge_dst,
    const float* __restrict__ Ai,
    const float* __restrict__ gw1, const float* __restrict__ gb1,
    const float* __restrict__ gw2, const float* __restrict__ gb2,
    const float* __restrict__ gw3, const float* __restrict__ gb3,
    const float* __restrict__ gw4, const float* __restrict__ gb4,
    float* __restrict__ out_acc, float* __restrict__ cnt, int n_edges)
{
    // per-thread h vector staged in LDS (own slice; no cross-thread sharing, no barriers)
    __shared__ float lds_h[64 * EBLK];
    int tid = threadIdx.x;
    int e = blockIdx.x * EBLK + tid;
    if (e >= n_edges) return;

    int src = edge_src[e];
    int dst = edge_dst[e];
    int b = batch[src];

    float es0 = edge_shifts[e * 3 + 0];
    float es1 = edge_shifts[e * 3 + 1];
    float es2 = edge_shifts[e * 3 + 2];
    const float* C = cell + b * 9;
    float vx = pos[dst * 3 + 0] - pos[src * 3 + 0] + es0 * C[0] + es1 * C[3] + es2 * C[6];
    float vy = pos[dst * 3 + 1] - pos[src * 3 + 1] + es0 * C[1] + es1 * C[4] + es2 * C[7];
    float vz = pos[dst * 3 + 2] - pos[src * 3 + 2] + es0 * C[2] + es1 * C[5] + es2 * C[8];

    float r2 = vx * vx + vy * vy + vz * vz + 1e-12f;
    float r = sqrtf(r2);
    float inv = 1.0f / r;
    float x = vx * inv, y = vy * inv, z = vz * inv;

    const float s3 = 1.7320508075688772f;
    const float s5 = 2.23606797749979f;
    const float s15 = 3.872983346207417f;
    float sh[9];
    sh[0] = 1.0f;
    sh[1] = s3 * x; sh[2] = s3 * y; sh[3] = s3 * z;
    sh[4] = s15 * x * y;
    sh[5] = s15 * y * z;
    sh[6] = 0.5f * s5 * (2.0f * z * z - x * x - y * y);
    sh[7] = s15 * x * z;
    sh[8] = 0.5f * s15 * (x * x - y * y);

    // radial embedding: NB=8, sigma=1/7, * sqrt(8), hard cutoff at RMAX
    float xr = fminf(r * 0.2f, 1.0f);
    float cutoff = (r <= 5.0f) ? 2.8284271247461903f : 0.0f;
    float emb[8];
#pragma unroll
    for (int k = 0; k < 8; ++k) {
        float d = (xr - (float)k * (1.0f / 7.0f)) * 7.0f;
        emb[k] = __expf(-0.5f * d * d) * cutoff;
    }

    // layer 1: 8 -> 64
    float h[64];
#pragma unroll
    for (int t = 0; t < 64; ++t) h[t] = gb1[t];
#pragma unroll
    for (int k = 0; k < 8; ++k) {
        float hk = emb[k];
#pragma unroll
        for (int t = 0; t < 64; ++t) h[t] += hk * gw1[k * 64 + t];
    }
#pragma unroll
    for (int t = 0; t < 64; ++t) lds_h[t * EBLK + tid] = silu_f(h[t]);

    // layer 2: 64 -> 64 (h1 read from LDS, row of gw2 is uniform -> scalar loads)
#pragma unroll
    for (int t = 0; t < 64; ++t) h[t] = gb2[t];
    for (int k = 0; k < 64; ++k) {
        float hk = lds_h[k * EBLK + tid];
#pragma unroll
        for (int t = 0; t < 64; ++t) h[t] += hk * gw2[k * 64 + t];
    }
#pragma unroll
    for (int t = 0; t < 64; ++t) lds_h[t * EBLK + tid] = silu_f(h[t]);

    // layer 3: 64 -> 64
#pragma unroll
    for (int t = 0; t < 64; ++t) h[t] = gb3[t];
    for (int k = 0; k < 64; ++k) {
        float hk = lds_h[k * EBLK + tid];
#pragma unroll
        for (int t = 0; t < 64; ++t) h[t] += hk * gw3[k * 64 + t];
    }
#pragma unroll
    for (int t = 0; t < 64; ++t) lds_h[t * EBLK + tid] = silu_f(h[t]);  // h3

    // c[i*8+j] = Ai[src][i] * Ai[dst][j]
    float c[64];
    {
        float As[8], Ad[8];
#pragma unroll
        for (int i = 0; i < 8; ++i) As[i] = Ai[src * 8 + i];
#pragma unroll
        for (int j = 0; j < 8; ++j) Ad[j] = Ai[dst * 8 + j];
#pragma unroll
        for (int i = 0; i < 8; ++i)
#pragma unroll
            for (int j = 0; j < 8; ++j) c[i * 8 + j] = As[i] * Ad[j];
    }

    float g[16];
#pragma unroll
    for (int u = 0; u < 16; ++u) g[u] = 0.0f;

    // bias row of last layer (h==1)
    accum_row(gb4, 1.0f, c, g);
    // main contraction: 64 rows of gw4
    for (int k = 0; k < 64; ++k) {
        float hk = lds_h[k * EBLK + tid];
        accum_row(gw4 + (k << 10), hk, c, g);
    }

    // epilogue: feat[e, :40] scattered into out_acc[dst]
    const float alpha = 0.125f;
    float* accp = out_acc + dst * 40;
#pragma unroll
    for (int u = 0; u < 8; ++u)
        atomicAdd(accp + u, alpha * g[u]);           // sh[0] == 1
#pragma unroll
    for (int u = 0; u < 4; ++u) {
        float gu = alpha * g[8 + u];
#pragma unroll
        for (int m2 = 0; m2 < 3; ++m2)
            atomicAdd(accp + 8 + u * 3 + m2, gu * sh[1 + m2]);
    }
#pragma unroll
    for (int u = 0; u < 4; ++u) {
        float gu = alpha * g[12 + u];
#pragma unroll
        for (int m2 = 0; m2 < 5; ++m2)
            atomicAdd(accp + 20 + u * 5 + m2, gu * sh[4 + m2]);
    }
    atomicAdd(cnt + dst, 1.0f);
}

// ---------------- finalize: out /= max(count,1) ----------------
__global__ __launch_bounds__(256) void finalize_kernel(
    float* __restrict__ out, const float* __restrict__ cnt, int total)
{
    int i = blockIdx.x * blockDim.x + threadIdx.x;
    if (i >= total) return;
    out[i] /= fmaxf(cnt[i / 40], 1.0f);
}

extern "C" void kernel_launch(void* const* d_in, const int* in_sizes, int n_in,
                              void* d_out, int out_size, void* d_ws, size_t ws_size,
                              hipStream_t stream)
{
    const float* pos         = (const float*)d_in[0];
    const float* edge_shifts = (const float*)d_in[1];
    const float* cell        = (const float*)d_in[2];
    const float* atom_table  = (const float*)d_in[3];
    const float* fw1 = (const float*)d_in[4];
    const float* fb1 = (const float*)d_in[5];
    const float* fw2 = (const float*)d_in[6];
    const float* fb2 = (const float*)d_in[7];
    const float* fw3 = (const float*)d_in[8];
    const float* fb3 = (const float*)d_in[9];
    const float* gw1 = (const float*)d_in[10];
    const float* gb1 = (const float*)d_in[11];
    const float* gw2 = (const float*)d_in[12];
    const float* gb2 = (const float*)d_in[13];
    const float* gw3 = (const float*)d_in[14];
    const float* gb3 = (const float*)d_in[15];
    const float* gw4 = (const float*)d_in[16];
    const float* gb4 = (const float*)d_in[17];
    const int* A        = (const int*)d_in[18];
    const int* batch    = (const int*)d_in[19];
    const int* edge_src = (const int*)d_in[20];
    const int* edge_dst = (const int*)d_in[21];

    int n_atoms = in_sizes[18];
    int n_edges = in_sizes[20];

    float* out = (float*)d_out;
    float* Ai  = (float*)d_ws;                 // n_atoms*8 floats
    float* cnt = Ai + (size_t)n_atoms * 8;     // n_atoms floats

    hipMemsetAsync(d_out, 0, sizeof(float) * (size_t)out_size, stream);
    hipMemsetAsync(cnt, 0, sizeof(float) * (size_t)n_atoms, stream);

    atoms_kernel<<<(n_atoms + 255) / 256, 256, 0, stream>>>(
        atom_table, A, fw1, fb1, fw2, fb2, fw3, fb3, Ai, n_atoms);

    edge_kernel<<<(n_edges + EBLK - 1) / EBLK, EBLK, 0, stream>>>(
        pos, edge_shifts, cell, batch, edge_src, edge_dst, Ai,
        gw1, gb1, gw2, gb2, gw3, gb3, gw4, gb4, out, cnt, n_edges);

    int total = n_atoms * 40;
    finalize_kernel<<<(total + 255) / 256, 256, 0, stream>>>(out, cnt, total);
}

// Round 2
// 1063.789 us; speedup vs baseline: 1.7634x; 1.7634x over previous
//
#include <hip/hip_runtime.h>
#include <math.h>

// N=25000, E=400000, S=8, NB=8, RMAX=5, EMB=16, MULS=(8,4,4), DIMS=(1,3,5), WNUM=1024
// g[e,u] = sum_p c[e,p] * ( sum_k h3[e,k] gw4[k, col(p,u)] + gb4[col(p,u)] )
// out[dst, feat(u,m)] += alpha * g[e,u] * sh[e, m-range(u)]  (then / count)

typedef __attribute__((ext_vector_type(8))) short short8;
typedef __attribute__((ext_vector_type(4))) float f32x4;

__device__ __forceinline__ float silu_f(float x) { return x / (1.0f + __expf(-x)); }

__device__ __forceinline__ unsigned short bf16r(float f) {
    union { float f; unsigned u; } v; v.f = f;
    return (unsigned short)((v.u + 0x7fffu + ((v.u >> 16) & 1u)) >> 16);
}

__device__ __forceinline__ int col_pu(int p, int u) {
    return (u < 8) ? (p * 8 + u)
         : (u < 12) ? (512 + p * 4 + (u - 8))
                    : (768 + p * 4 + (u - 12));
}

// ---------------- Atom MLP: 16 -> 64 -> 32 -> 8 ----------------
__global__ __launch_bounds__(256) void atoms_kernel(
    const float* __restrict__ atom_table, const int* __restrict__ A,
    const float* __restrict__ fw1, const float* __restrict__ fb1,
    const float* __restrict__ fw2, const float* __restrict__ fb2,
    const float* __restrict__ fw3, const float* __restrict__ fb3,
    float* __restrict__ Ai, int n_atoms)
{
    int n = blockIdx.x * blockDim.x + threadIdx.x;
    if (n >= n_atoms) return;
    const float* at = atom_table + A[n] * 16;

    float h1[64];
#pragma unroll
    for (int t = 0; t < 64; ++t) h1[t] = fb1[t];
#pragma unroll
    for (int k = 0; k < 16; ++k) {
        float x = at[k];
#pragma unroll
        for (int t = 0; t < 64; ++t) h1[t] += x * fw1[k * 64 + t];
    }
#pragma unroll
    for (int t = 0; t < 64; ++t) h1[t] = silu_f(h1[t]);

    float h2[32];
#pragma unroll
    for (int t = 0; t < 32; ++t) h2[t] = fb2[t];
#pragma unroll
    for (int k = 0; k < 64; ++k) {
        float x = h1[k];
#pragma unroll
        for (int t = 0; t < 32; ++t) h2[t] += x * fw2[k * 32 + t];
    }
#pragma unroll
    for (int t = 0; t < 32; ++t) h2[t] = silu_f(h2[t]);

    float o[8];
#pragma unroll
    for (int t = 0; t < 8; ++t) o[t] = fb3[t];
#pragma unroll
    for (int k = 0; k < 32; ++k) {
        float x = h2[k];
#pragma unroll
        for (int t = 0; t < 8; ++t) o[t] += x * fw3[k * 8 + t];
    }
#pragma unroll
    for (int t = 0; t < 8; ++t) Ai[n * 8 + t] = o[t];
}

// ---------------- prep: permute gw4 -> W4pk[p][u][k] bf16, gb4 -> gb4T[u][p] bf16 ----
__global__ __launch_bounds__(256) void prep_kernel(
    const float* __restrict__ gw4, const float* __restrict__ gb4,
    unsigned short* __restrict__ W4pk, unsigned short* __restrict__ gb4T)
{
    int idx = blockIdx.x * 256 + threadIdx.x;
    if (idx < 65536) {
        int p = idx >> 10, u = (idx >> 6) & 15, k = idx & 63;
        W4pk[idx] = bf16r(gw4[k * 1024 + col_pu(p, u)]);
    } else if (idx < 66560) {
        int i2 = idx - 65536;
        int u = i2 >> 6, p = i2 & 63;
        gb4T[i2] = bf16r(gb4[col_pu(p, u)]);
    }
}

// ---------------- radial MLP per edge: emb(8) -> 64 -> 64 -> 64, h3 -> bf16 ----------
__global__ __launch_bounds__(256) void edge_mlp_kernel(
    const float* __restrict__ pos, const float* __restrict__ edge_shifts,
    const float* __restrict__ cell, const int* __restrict__ batch,
    const int* __restrict__ edge_src, const int* __restrict__ edge_dst,
    const float* __restrict__ gw1, const float* __restrict__ gb1,
    const float* __restrict__ gw2, const float* __restrict__ gb2,
    const float* __restrict__ gw3, const float* __restrict__ gb3,
    unsigned short* __restrict__ h3g, float* __restrict__ cnt, int n_edges)
{
    int e = blockIdx.x * 256 + threadIdx.x;
    if (e >= n_edges) return;

    int src = edge_src[e];
    int dst = edge_dst[e];
    atomicAdd(cnt + dst, 1.0f);

    int b = batch[src];
    const float* C = cell + b * 9;
    float es0 = edge_shifts[e * 3 + 0];
    float es1 = edge_shifts[e * 3 + 1];
    float es2 = edge_shifts[e * 3 + 2];
    float vx = pos[dst * 3 + 0] - pos[src * 3 + 0] + es0 * C[0] + es1 * C[3] + es2 * C[6];
    float vy = pos[dst * 3 + 1] - pos[src * 3 + 1] + es0 * C[1] + es1 * C[4] + es2 * C[7];
    float vz = pos[dst * 3 + 2] - pos[src * 3 + 2] + es0 * C[2] + es1 * C[5] + es2 * C[8];
    float r = sqrtf(vx * vx + vy * vy + vz * vz + 1e-12f);

    float xr = fminf(r * 0.2f, 1.0f);
    float cutoff = (r <= 5.0f) ? 2.8284271247461903f : 0.0f;
    float emb[8];
#pragma unroll
    for (int k = 0; k < 8; ++k) {
        float d = (xr - (float)k * (1.0f / 7.0f)) * 7.0f;
        emb[k] = __expf(-0.5f * d * d) * cutoff;
    }

    float ha[64], hb[64];
#pragma unroll
    for (int t = 0; t < 64; ++t) ha[t] = gb1[t];
#pragma unroll
    for (int k = 0; k < 8; ++k) {
        float hk = emb[k];
#pragma unroll
        for (int t = 0; t < 64; ++t) ha[t] += hk * gw1[k * 64 + t];
    }
#pragma unroll
    for (int t = 0; t < 64; ++t) ha[t] = silu_f(ha[t]);

#pragma unroll
    for (int t = 0; t < 64; ++t) hb[t] = gb2[t];
#pragma unroll
    for (int k = 0; k < 64; ++k) {
        float hk = ha[k];
#pragma unroll
        for (int t = 0; t < 64; ++t) hb[t] += hk * gw2[k * 64 + t];
    }
#pragma unroll
    for (int t = 0; t < 64; ++t) hb[t] = silu_f(hb[t]);

#pragma unroll
    for (int t = 0; t < 64; ++t) ha[t] = gb3[t];
#pragma unroll
    for (int k = 0; k < 64; ++k) {
        float hk = hb[k];
#pragma unroll
        for (int t = 0; t < 64; ++t) ha[t] += hk * gw3[k * 64 + t];
    }

    unsigned pk[32];
#pragma unroll
    for (int t = 0; t < 32; ++t) {
        unsigned lo = bf16r(silu_f(ha[2 * t]));
        unsigned hi = bf16r(silu_f(ha[2 * t + 1]));
        pk[t] = lo | (hi << 16);
    }
    uint4* op = (uint4*)(h3g + (size_t)e * 64);
#pragma unroll
    for (int q = 0; q < 8; ++q)
        op[q] = make_uint4(pk[4 * q], pk[4 * q + 1], pk[4 * q + 2], pk[4 * q + 3]);
}

// ---------------- MFMA contraction + scatter ----------------
// block = 256 (4 waves), each wave owns 16 edges. Per wave:
//   D_p[e,u] = sum_k h3[e,k] W4pk[p,u,k]   (2 MFMA per p)
//   g[e,u]  += c[e,p] * D_p[e,u]           (ds_read_b128 + 4 fmac)
//   bias: g += (c @ gb4T) via 2 MFMA
__global__ __launch_bounds__(256) void edge_mfma_kernel(
    const float* __restrict__ pos, const float* __restrict__ edge_shifts,
    const float* __restrict__ cell, const int* __restrict__ batch,
    const int* __restrict__ edge_src, const int* __restrict__ edge_dst,
    const float* __restrict__ Ai, const unsigned short* __restrict__ h3g,
    const unsigned short* __restrict__ W4pk, const unsigned short* __restrict__ gb4T,
    float* __restrict__ out_acc, int n_edges)
{
    __shared__ float lds_sh[64 * 16];   // sh[el][0..8], stride 16
    __shared__ int   lds_dst[64];
    __shared__ float lds_As[64 * 8];
    __shared__ float lds_Ad[64 * 8];
    __shared__ float lds_c[4 * 1024];   // [wave][p*16 + e_local]

    int tid = threadIdx.x;
    int eb = blockIdx.x * 64;

    if (tid < 64) {
        int ec = min(eb + tid, n_edges - 1);
        int src = edge_src[ec], dst = edge_dst[ec];
        lds_dst[tid] = dst;
        int b = batch[src];
        const float* C = cell + b * 9;
        float es0 = edge_shifts[ec * 3 + 0];
        float es1 = edge_shifts[ec * 3 + 1];
        float es2 = edge_shifts[ec * 3 + 2];
        float vx = pos[dst * 3 + 0] - pos[src * 3 + 0] + es0 * C[0] + es1 * C[3] + es2 * C[6];
        float vy = pos[dst * 3 + 1] - pos[src * 3 + 1] + es0 * C[1] + es1 * C[4] + es2 * C[7];
        float vz = pos[dst * 3 + 2] - pos[src * 3 + 2] + es0 * C[2] + es1 * C[5] + es2 * C[8];
        float inv = rsqrtf(vx * vx + vy * vy + vz * vz + 1e-12f);
        float x = vx * inv, y = vy * inv, z = vz * inv;
        const float s3 = 1.7320508075688772f;
        const float s5 = 2.23606797749979f;
        const float s15 = 3.872983346207417f;
        float* shp = lds_sh + tid * 16;
        shp[0] = 1.0f;
        shp[1] = s3 * x; shp[2] = s3 * y; shp[3] = s3 * z;
        shp[4] = s15 * x * y;
        shp[5] = s15 * y * z;
        shp[6] = 0.5f * s5 * (2.0f * z * z - x * x - y * y);
        shp[7] = s15 * x * z;
        shp[8] = 0.5f * s15 * (x * x - y * y);
    } else if (tid < 128) {
        int t = tid - 64;
        int ec = min(eb + t, n_edges - 1);
        int s = edge_src[ec];
        const float4* r4 = (const float4*)(Ai + s * 8);
        ((float4*)lds_As)[t * 2] = r4[0];
        ((float4*)lds_As)[t * 2 + 1] = r4[1];
    } else if (tid < 192) {
        int t = tid - 128;
        int ec = min(eb + t, n_edges - 1);
        int s = edge_dst[ec];
        const float4* r4 = (const float4*)(Ai + s * 8);
        ((float4*)lds_Ad)[t * 2] = r4[0];
        ((float4*)lds_Ad)[t * 2 + 1] = r4[1];
    }
    __syncthreads();

    int wave = tid >> 6, lane = tid & 63;
    int quad = lane >> 4, col = lane & 15;
    int el = wave * 16 + col;   // block-local edge index on the A/m side

    // fill lds_c[wave][p*16 + e] : lane covers e=col, p in [quad*16, quad*16+16)
    {
        float as0 = lds_As[el * 8 + quad * 2];
        float as1 = lds_As[el * 8 + quad * 2 + 1];
        float4 ad0 = ((const float4*)lds_Ad)[el * 2];
        float4 ad1 = ((const float4*)lds_Ad)[el * 2 + 1];
        float ad[8] = {ad0.x, ad0.y, ad0.z, ad0.w, ad1.x, ad1.y, ad1.z, ad1.w};
        float* cw = &lds_c[wave * 1024 + (quad * 16) * 16 + col];
#pragma unroll
        for (int i2 = 0; i2 < 16; ++i2) {
            float asv = (i2 < 8) ? as0 : as1;
            cw[i2 * 16] = asv * ad[i2 & 7];
        }
    }

    // A-frags: h3 (m = col, k = kh*32 + quad*8 + j), straight from global
    const unsigned short* h3p = h3g + (size_t)min(eb + el, n_edges - 1) * 64 + quad * 8;
    short8 aH0 = *(const short8*)(h3p);
    short8 aH1 = *(const short8*)(h3p + 32);

    // A-frags for bias GEMM: c[e=col][k=p], elem j = As[col][kh*4+quad]*Ad[col][j]
    short8 aC0, aC1;
    {
        float a0 = lds_As[el * 8 + quad];
        float a1 = lds_As[el * 8 + 4 + quad];
        float4 ad0 = ((const float4*)lds_Ad)[el * 2];
        float4 ad1 = ((const float4*)lds_Ad)[el * 2 + 1];
        float ad[8] = {ad0.x, ad0.y, ad0.z, ad0.w, ad1.x, ad1.y, ad1.z, ad1.w};
#pragma unroll
        for (int j = 0; j < 8; ++j) {
            aC0[j] = (short)bf16r(a0 * ad[j]);
            aC1[j] = (short)bf16r(a1 * ad[j]);
        }
    }

    // bias GEMM: g = c @ gb4T   (B[n=col][k=quad*8+j] = gb4T[col*64 + k])
    f32x4 g;
    {
        const unsigned short* bp = gb4T + col * 64 + quad * 8;
        short8 b0 = *(const short8*)(bp);
        short8 b1 = *(const short8*)(bp + 32);
        f32x4 d = {0.0f, 0.0f, 0.0f, 0.0f};
        d = __builtin_amdgcn_mfma_f32_16x16x32_bf16(aC0, b0, d, 0, 0, 0);
        d = __builtin_amdgcn_mfma_f32_16x16x32_bf16(aC1, b1, d, 0, 0, 0);
        g = d;
    }

    // main loop over p
    const float* cbase = &lds_c[wave * 1024 + quad * 4];
    const unsigned short* wb = W4pk + col * 64 + quad * 8;
#pragma unroll 4
    for (int p = 0; p < 64; ++p) {
        const unsigned short* bp = wb + p * 1024;
        short8 b0 = *(const short8*)(bp);
        short8 b1 = *(const short8*)(bp + 32);
        f32x4 d = {0.0f, 0.0f, 0.0f, 0.0f};
        d = __builtin_amdgcn_mfma_f32_16x16x32_bf16(aH0, b0, d, 0, 0, 0);
        d = __builtin_amdgcn_mfma_f32_16x16x32_bf16(aH1, b1, d, 0, 0, 0);
        f32x4 cv = *(const f32x4*)(cbase + p * 16);
        g.x += cv.x * d.x;
        g.y += cv.y * d.y;
        g.z += cv.z * d.z;
        g.w += cv.w * d.w;
    }

    // epilogue: lane holds g[e = quad*4+r][u = col]
    const float alpha = 0.125f;
    float garr[4] = {g.x, g.y, g.z, g.w};
    int u = col;
#pragma unroll
    for (int r = 0; r < 4; ++r) {
        int elr = wave * 16 + quad * 4 + r;
        int ge = eb + elr;
        if (ge >= n_edges) continue;
        float gv = alpha * garr[r];
        float* op = out_acc + (size_t)lds_dst[elr] * 40;
        const float* shp = lds_sh + elr * 16;
        if (u < 8) {
            atomicAdd(op + u, gv);
        } else if (u < 12) {
            int m = u - 8;
#pragma unroll
            for (int t = 0; t < 3; ++t)
                atomicAdd(op + 8 + m * 3 + t, gv * shp[1 + t]);
        } else {
            int m = u - 12;
#pragma unroll
            for (int t = 0; t < 5; ++t)
                atomicAdd(op + 20 + m * 5 + t, gv * shp[4 + t]);
        }
    }
}

// ---------------- finalize ----------------
__global__ __launch_bounds__(256) void finalize_kernel(
    float* __restrict__ out, const float* __restrict__ cnt, int total)
{
    int i = blockIdx.x * blockDim.x + threadIdx.x;
    if (i >= total) return;
    out[i] /= fmaxf(cnt[i / 40], 1.0f);
}

static inline size_t align256(size_t x) { return (x + 255) & ~(size_t)255; }

extern "C" void kernel_launch(void* const* d_in, const int* in_sizes, int n_in,
                              void* d_out, int out_size, void* d_ws, size_t ws_size,
                              hipStream_t stream)
{
    const float* pos         = (const float*)d_in[0];
    const float* edge_shifts = (const float*)d_in[1];
    const float* cell        = (const float*)d_in[2];
    const float* atom_table  = (const float*)d_in[3];
    const float* fw1 = (const float*)d_in[4];
    const float* fb1 = (const float*)d_in[5];
    const float* fw2 = (const float*)d_in[6];
    const float* fb2 = (const float*)d_in[7];
    const float* fw3 = (const float*)d_in[8];
    const float* fb3 = (const float*)d_in[9];
    const float* gw1 = (const float*)d_in[10];
    const float* gb1 = (const float*)d_in[11];
    const float* gw2 = (const float*)d_in[12];
    const float* gb2 = (const float*)d_in[13];
    const float* gw3 = (const float*)d_in[14];
    const float* gb3 = (const float*)d_in[15];
    const float* gw4 = (const float*)d_in[16];
    const float* gb4 = (const float*)d_in[17];
    const int* A        = (const int*)d_in[18];
    const int* batch    = (const int*)d_in[19];
    const int* edge_src = (const int*)d_in[20];
    const int* edge_dst = (const int*)d_in[21];

    int n_atoms = in_sizes[18];
    int n_edges = in_sizes[20];

    char* w = (char*)d_ws;
    float* Ai = (float*)w;                  w += align256((size_t)n_atoms * 8 * 4);
    float* cnt = (float*)w;                 w += align256((size_t)n_atoms * 4);
    unsigned short* h3g = (unsigned short*)w;  w += align256((size_t)n_edges * 64 * 2);
    unsigned short* W4pk = (unsigned short*)w; w += align256((size_t)65536 * 2);
    unsigned short* gb4T = (unsigned short*)w; w += align256((size_t)1024 * 2);

    float* out = (float*)d_out;
    hipMemsetAsync(d_out, 0, sizeof(float) * (size_t)out_size, stream);
    hipMemsetAsync(cnt, 0, sizeof(float) * (size_t)n_atoms, stream);

    prep_kernel<<<(66560 + 255) / 256, 256, 0, stream>>>(gw4, gb4, W4pk, gb4T);

    atoms_kernel<<<(n_atoms + 255) / 256, 256, 0, stream>>>(
        atom_table, A, fw1, fb1, fw2, fb2, fw3, fb3, Ai, n_atoms);

    edge_mlp_kernel<<<(n_edges + 255) / 256, 256, 0, stream>>>(
        pos, edge_shifts, cell, batch, edge_src, edge_dst,
        gw1, gb1, gw2, gb2, gw3, gb3, h3g, cnt, n_edges);

    edge_mfma_kernel<<<(n_edges + 63) / 64, 256, 0, stream>>>(
        pos, edge_shifts, cell, batch, edge_src, edge_dst,
        Ai, h3g, W4pk, gb4T, out, n_edges);

    int total = n_atoms * 40;
    finalize_kernel<<<(total + 255) / 256, 256, 0, stream>>>(out, cnt, total);
}

// Round 3
// 619.065 us; speedup vs baseline: 3.0302x; 1.7184x over previous
//
#include <hip/hip_runtime.h>
#include <math.h>

// N=25000, E=400000, S=8, NB=8, RMAX=5, EMB=16, MULS=(8,4,4), DIMS=(1,3,5), WNUM=1024
// g[e,u] = sum_p c[e,p] * ( sum_k h3[e,k] gw4[k, col(p,u)] + gb4[col(p,u)] )
// out[dst, feat(u,m)] += alpha * g[e,u] * sh[e, m]  (then / count)

typedef __attribute__((ext_vector_type(8))) short short8;
typedef __attribute__((ext_vector_type(4))) float f32x4;

__device__ __forceinline__ float silu_f(float x) { return x / (1.0f + __expf(-x)); }

__device__ __forceinline__ unsigned short bf16r(float f) {
    union { float f; unsigned u; } v; v.f = f;
    return (unsigned short)((v.u + 0x7fffu + ((v.u >> 16) & 1u)) >> 16);
}
__device__ __forceinline__ unsigned pack2(float lo, float hi) {
    return (unsigned)bf16r(lo) | ((unsigned)bf16r(hi) << 16);
}
__device__ __forceinline__ float bflo(unsigned u) {
    union { unsigned u; float f; } v; v.u = u << 16; return v.f;
}
__device__ __forceinline__ float bfhi(unsigned u) {
    union { unsigned u; float f; } v; v.u = u & 0xffff0000u; return v.f;
}
__device__ __forceinline__ int col_pu(int p, int u) {
    return (u < 8) ? (p * 8 + u)
         : (u < 12) ? (512 + p * 4 + (u - 8))
                    : (768 + p * 4 + (u - 12));
}

// ---------------- Atom MLP: 16 -> 64 -> 32 -> 8 ----------------
__global__ __launch_bounds__(256) void atoms_kernel(
    const float* __restrict__ atom_table, const int* __restrict__ A,
    const float* __restrict__ fw1, const float* __restrict__ fb1,
    const float* __restrict__ fw2, const float* __restrict__ fb2,
    const float* __restrict__ fw3, const float* __restrict__ fb3,
    float* __restrict__ Ai, int n_atoms)
{
    int n = blockIdx.x * blockDim.x + threadIdx.x;
    if (n >= n_atoms) return;
    const float* at = atom_table + A[n] * 16;

    float h1[64];
#pragma unroll
    for (int t = 0; t < 64; ++t) h1[t] = fb1[t];
#pragma unroll
    for (int k = 0; k < 16; ++k) {
        float x = at[k];
#pragma unroll
        for (int t = 0; t < 64; ++t) h1[t] += x * fw1[k * 64 + t];
    }
#pragma unroll
    for (int t = 0; t < 64; ++t) h1[t] = silu_f(h1[t]);

    float h2[32];
#pragma unroll
    for (int t = 0; t < 32; ++t) h2[t] = fb2[t];
#pragma unroll
    for (int k = 0; k < 64; ++k) {
        float x = h1[k];
#pragma unroll
        for (int t = 0; t < 32; ++t) h2[t] += x * fw2[k * 32 + t];
    }
#pragma unroll
    for (int t = 0; t < 32; ++t) h2[t] = silu_f(h2[t]);

    float o[8];
#pragma unroll
    for (int t = 0; t < 8; ++t) o[t] = fb3[t];
#pragma unroll
    for (int k = 0; k < 32; ++k) {
        float x = h2[k];
#pragma unroll
        for (int t = 0; t < 8; ++t) o[t] += x * fw3[k * 8 + t];
    }
#pragma unroll
    for (int t = 0; t < 8; ++t) Ai[n * 8 + t] = o[t];
}

// ---------------- prep: W4pk[p][u][k], gw2T/gw3T[n][k] bf16, gb4pu[p][u] f32 ------
__global__ __launch_bounds__(256) void prep_kernel(
    const float* __restrict__ gw4, const float* __restrict__ gb4,
    const float* __restrict__ gw2, const float* __restrict__ gw3,
    unsigned short* __restrict__ W4pk, unsigned short* __restrict__ gw2T,
    unsigned short* __restrict__ gw3T, float* __restrict__ gb4pu)
{
    int idx = blockIdx.x * 256 + threadIdx.x;
    if (idx < 65536) {
        int p = idx >> 10, u = (idx >> 6) & 15, k = idx & 63;
        W4pk[idx] = bf16r(gw4[k * 1024 + col_pu(p, u)]);
    } else if (idx < 69632) {
        int t = idx - 65536; int n = t >> 6, k = t & 63;
        gw2T[t] = bf16r(gw2[k * 64 + n]);
    } else if (idx < 73728) {
        int t = idx - 69632; int n = t >> 6, k = t & 63;
        gw3T[t] = bf16r(gw3[k * 64 + n]);
    } else if (idx < 74752) {
        int t = idx - 73728; int p = t >> 4, u = t & 15;
        gb4pu[t] = gb4[col_pu(p, u)];
    }
}

// ---------------- radial MLP via MFMA: emb(8) ->64(fp32) ->64 ->64, h3 -> bf16 -----
// block = 256 (4 waves), 64 edges/block, 16 edges/wave.
__global__ __launch_bounds__(256) void edge_mlp_mfma(
    const float* __restrict__ pos, const float* __restrict__ edge_shifts,
    const float* __restrict__ cell, const int* __restrict__ batch,
    const int* __restrict__ edge_src, const int* __restrict__ edge_dst,
    const float* __restrict__ gw1, const float* __restrict__ gb1,
    const float* __restrict__ gb2, const float* __restrict__ gb3,
    const unsigned short* __restrict__ gw2T, const unsigned short* __restrict__ gw3T,
    unsigned short* __restrict__ h3g, int n_edges)
{
    __shared__ float s_emb[64][8];
    __shared__ unsigned short s_h[4][16][72];   // per-wave h buffer, row stride 72 bf16 (144 B)

    int tid = threadIdx.x;
    int eb = blockIdx.x * 64;

    if (tid < 64) {
        int ec = min(eb + tid, n_edges - 1);
        int src = edge_src[ec], dst = edge_dst[ec];
        int b = batch[src];
        const float* C = cell + b * 9;
        float es0 = edge_shifts[ec * 3 + 0];
        float es1 = edge_shifts[ec * 3 + 1];
        float es2 = edge_shifts[ec * 3 + 2];
        float vx = pos[dst * 3 + 0] - pos[src * 3 + 0] + es0 * C[0] + es1 * C[3] + es2 * C[6];
        float vy = pos[dst * 3 + 1] - pos[src * 3 + 1] + es0 * C[1] + es1 * C[4] + es2 * C[7];
        float vz = pos[dst * 3 + 2] - pos[src * 3 + 2] + es0 * C[2] + es1 * C[5] + es2 * C[8];
        float r = sqrtf(vx * vx + vy * vy + vz * vz + 1e-12f);
        float xr = fminf(r * 0.2f, 1.0f);
        float cutoff = (r <= 5.0f) ? 2.8284271247461903f : 0.0f;
#pragma unroll
        for (int k = 0; k < 8; ++k) {
            float d = (xr - (float)k * (1.0f / 7.0f)) * 7.0f;
            s_emb[tid][k] = __expf(-0.5f * d * d) * cutoff;
        }
    }
    __syncthreads();

    int wave = tid >> 6, lane = tid & 63, quad = lane >> 4, col = lane & 15;
    int e_loc = wave * 16 + col;

    // ---- layer 1 (fp32 VALU): lane computes h1[e=col][n=quad*16 .. +16]
    {
        const float4* ep = (const float4*)s_emb[e_loc];
        float4 ea = ep[0], eb4 = ep[1];
        float emb0[8] = {ea.x, ea.y, ea.z, ea.w, eb4.x, eb4.y, eb4.z, eb4.w};

        float h1[16];
        {
            const float4* bp = (const float4*)(gb1 + quad * 16);
#pragma unroll
            for (int q = 0; q < 4; ++q) {
                float4 b = bp[q];
                h1[q * 4 + 0] = b.x; h1[q * 4 + 1] = b.y; h1[q * 4 + 2] = b.z; h1[q * 4 + 3] = b.w;
            }
        }
#pragma unroll
        for (int k = 0; k < 8; ++k) {
            float hk = emb0[k];
            const float4* wp = (const float4*)(gw1 + k * 64 + quad * 16);
#pragma unroll
            for (int q = 0; q < 4; ++q) {
                float4 wv = wp[q];
                h1[q * 4 + 0] += hk * wv.x;
                h1[q * 4 + 1] += hk * wv.y;
                h1[q * 4 + 2] += hk * wv.z;
                h1[q * 4 + 3] += hk * wv.w;
            }
        }
        unsigned pk[8];
#pragma unroll
        for (int t = 0; t < 8; ++t)
            pk[t] = pack2(silu_f(h1[2 * t]), silu_f(h1[2 * t + 1]));
        uint4* wp0 = (uint4*)&s_h[wave][col][quad * 16];
        wp0[0] = make_uint4(pk[0], pk[1], pk[2], pk[3]);
        wp0[1] = make_uint4(pk[4], pk[5], pk[6], pk[7]);
    }
    __syncthreads();

    // ---- layers 2 and 3 (MFMA), identical structure
#pragma unroll 1
    for (int layer = 0; layer < 2; ++layer) {
        const unsigned short* WT = layer ? gw3T : gw2T;
        const float* gb = layer ? gb3 : gb2;

        short8 a0 = *(const short8*)&s_h[wave][col][quad * 8];
        short8 a1 = *(const short8*)&s_h[wave][col][32 + quad * 8];

        float hv[16];
#pragma unroll
        for (int nt = 0; nt < 4; ++nt) {
            int n = nt * 16 + col;
            short8 b0 = *(const short8*)(WT + n * 64 + quad * 8);
            short8 b1 = *(const short8*)(WT + n * 64 + 32 + quad * 8);
            float bb = gb[n];
            f32x4 d = {bb, bb, bb, bb};
            d = __builtin_amdgcn_mfma_f32_16x16x32_bf16(a0, b0, d, 0, 0, 0);
            d = __builtin_amdgcn_mfma_f32_16x16x32_bf16(a1, b1, d, 0, 0, 0);
            hv[nt * 4 + 0] = silu_f(d[0]);
            hv[nt * 4 + 1] = silu_f(d[1]);
            hv[nt * 4 + 2] = silu_f(d[2]);
            hv[nt * 4 + 3] = silu_f(d[3]);
        }
        __syncthreads();   // everyone done reading s_h as A-frags
#pragma unroll
        for (int nt = 0; nt < 4; ++nt)
#pragma unroll
            for (int r = 0; r < 4; ++r)
                s_h[wave][quad * 4 + r][nt * 16 + col] = bf16r(hv[nt * 4 + r]);
        __syncthreads();
    }

    // ---- write h3 to global (coalesced)
    {
        int e2 = lane >> 2, seg = lane & 3;
        const uint4* sp = (const uint4*)((const char*)s_h[wave] + e2 * 144 + seg * 32);
        uint4 v0 = sp[0], v1 = sp[1];
        int ge = min(eb + wave * 16 + e2, n_edges - 1);
        uint4* dp = (uint4*)(h3g + (size_t)ge * 64 + seg * 16);
        dp[0] = v0; dp[1] = v1;
    }
}

// ---------------- contraction + scatter ----------------
// block = 256 (4 waves), 256 edges/block, 64 edges/wave (4 subtiles of 16).
// Per p: one B-pair + bias init feeds 8 MFMAs; c-fold via broadcast ds_read_b64.
__global__ __launch_bounds__(256, 2) void edge_contract(
    const float* __restrict__ pos, const float* __restrict__ edge_shifts,
    const float* __restrict__ cell, const int* __restrict__ batch,
    const int* __restrict__ edge_src, const int* __restrict__ edge_dst,
    const float* __restrict__ Ai, const unsigned short* __restrict__ h3g,
    const unsigned short* __restrict__ W4pk, const float* __restrict__ gb4pu,
    float* __restrict__ out_acc, float* __restrict__ cnt, int n_edges)
{
    __shared__ float s_sh[256][12];           // 12 KB
    __shared__ int   s_dst[256];              // 1 KB
    __shared__ float s_As[8][264];            // 8.25 KB (transposed Ai[src])
    __shared__ float s_Ad[8][264];            // 8.25 KB
    __shared__ unsigned short s_c[64][264];   // 33 KB, [p][e] bf16, row 528 B

    int tid = threadIdx.x;
    int eb = blockIdx.x * 256;

    {   // phase 0: one edge per thread — geometry + Ai staging
        int ge = eb + tid;
        int ec = min(ge, n_edges - 1);
        int src = edge_src[ec], dst = edge_dst[ec];
        s_dst[tid] = dst;
        int b = batch[src];
        const float* C = cell + b * 9;
        float es0 = edge_shifts[ec * 3 + 0];
        float es1 = edge_shifts[ec * 3 + 1];
        float es2 = edge_shifts[ec * 3 + 2];
        float vx = pos[dst * 3 + 0] - pos[src * 3 + 0] + es0 * C[0] + es1 * C[3] + es2 * C[6];
        float vy = pos[dst * 3 + 1] - pos[src * 3 + 1] + es0 * C[1] + es1 * C[4] + es2 * C[7];
        float vz = pos[dst * 3 + 2] - pos[src * 3 + 2] + es0 * C[2] + es1 * C[5] + es2 * C[8];
        float inv = rsqrtf(vx * vx + vy * vy + vz * vz + 1e-12f);
        float x = vx * inv, y = vy * inv, z = vz * inv;
        const float s3 = 1.7320508075688772f;
        const float s5 = 2.23606797749979f;
        const float s15 = 3.872983346207417f;
        s_sh[tid][0] = 1.0f;
        s_sh[tid][1] = s3 * x; s_sh[tid][2] = s3 * y; s_sh[tid][3] = s3 * z;
        s_sh[tid][4] = s15 * x * y;
        s_sh[tid][5] = s15 * y * z;
        s_sh[tid][6] = 0.5f * s5 * (2.0f * z * z - x * x - y * y);
        s_sh[tid][7] = s15 * x * z;
        s_sh[tid][8] = 0.5f * s15 * (x * x - y * y);
        if (ge < n_edges) atomicAdd(cnt + dst, 1.0f);

        const float4* asp = (const float4*)(Ai + (size_t)src * 8);
        float4 A0 = asp[0], A1 = asp[1];
        s_As[0][tid] = A0.x; s_As[1][tid] = A0.y; s_As[2][tid] = A0.z; s_As[3][tid] = A0.w;
        s_As[4][tid] = A1.x; s_As[5][tid] = A1.y; s_As[6][tid] = A1.z; s_As[7][tid] = A1.w;
        const float4* adp = (const float4*)(Ai + (size_t)dst * 8);
        float4 B0 = adp[0], B1 = adp[1];
        s_Ad[0][tid] = B0.x; s_Ad[1][tid] = B0.y; s_Ad[2][tid] = B0.z; s_Ad[3][tid] = B0.w;
        s_Ad[4][tid] = B1.x; s_Ad[5][tid] = B1.y; s_Ad[6][tid] = B1.z; s_Ad[7][tid] = B1.w;
    }
    __syncthreads();

    {   // phase 1: build c[p][e] bf16. wave w fills e-range [w*64, w*64+64), lane = p.
        int w = tid >> 6, p = tid & 63;
        int i = p >> 3, j = p & 7;
        const float* Ap = s_As[i] + w * 64;
        const float* Bp = s_Ad[j] + w * 64;
        char* crow = (char*)s_c + p * 528 + w * 128;
#pragma unroll
        for (int ch = 0; ch < 4; ++ch) {
            const float4* a4 = (const float4*)(Ap + ch * 16);
            const float4* b4 = (const float4*)(Bp + ch * 16);
            unsigned pk[8];
#pragma unroll
            for (int q = 0; q < 2; ++q) {
                float4 a0 = a4[q * 2], a1 = a4[q * 2 + 1];
                float4 b0 = b4[q * 2], b1 = b4[q * 2 + 1];
                pk[q * 4 + 0] = pack2(a0.x * b0.x, a0.y * b0.y);
                pk[q * 4 + 1] = pack2(a0.z * b0.z, a0.w * b0.w);
                pk[q * 4 + 2] = pack2(a1.x * b1.x, a1.y * b1.y);
                pk[q * 4 + 3] = pack2(a1.z * b1.z, a1.w * b1.w);
            }
            uint4* wp = (uint4*)(crow + ch * 32);
            wp[0] = make_uint4(pk[0], pk[1], pk[2], pk[3]);
            wp[1] = make_uint4(pk[4], pk[5], pk[6], pk[7]);
        }
    }
    __syncthreads();

    // phase 2: MFMA p-loop
    int w = tid >> 6, lane = tid & 63, quad = lane >> 4, col = lane & 15;

    short8 aH0[4], aH1[4];
#pragma unroll
    for (int s = 0; s < 4; ++s) {
        int ge = min(eb + w * 64 + s * 16 + col, n_edges - 1);
        const unsigned short* hp = h3g + (size_t)ge * 64 + quad * 8;
        aH0[s] = *(const short8*)hp;
        aH1[s] = *(const short8*)(hp + 32);
    }

    f32x4 g[4];
#pragma unroll
    for (int s = 0; s < 4; ++s) g[s] = (f32x4){0.0f, 0.0f, 0.0f, 0.0f};

    const unsigned short* wb = W4pk + col * 64 + quad * 8;
    const char* cbase = (const char*)s_c + w * 128 + quad * 8;

#pragma unroll 2
    for (int p = 0; p < 64; ++p) {
        short8 b0 = *(const short8*)(wb + p * 1024);
        short8 b1 = *(const short8*)(wb + p * 1024 + 32);
        float bb = gb4pu[p * 16 + col];
        f32x4 binit = {bb, bb, bb, bb};
        const char* crow = cbase + p * 528;
#pragma unroll
        for (int s = 0; s < 4; ++s) {
            f32x4 d = binit;
            d = __builtin_amdgcn_mfma_f32_16x16x32_bf16(aH0[s], b0, d, 0, 0, 0);
            d = __builtin_amdgcn_mfma_f32_16x16x32_bf16(aH1[s], b1, d, 0, 0, 0);
            uint2 cc = *(const uint2*)(crow + s * 32);
            g[s].x += bflo(cc.x) * d.x;
            g[s].y += bfhi(cc.x) * d.y;
            g[s].z += bflo(cc.y) * d.z;
            g[s].w += bfhi(cc.y) * d.w;
        }
    }

    // epilogue: atomic scatter
    const float alpha = 0.125f;
#pragma unroll
    for (int s = 0; s < 4; ++s) {
        float garr[4] = {g[s].x, g[s].y, g[s].z, g[s].w};
#pragma unroll
        for (int r = 0; r < 4; ++r) {
            int el = w * 64 + s * 16 + quad * 4 + r;
            int ge = eb + el;
            if (ge >= n_edges) continue;
            float gv = alpha * garr[r];
            float* op = out_acc + (size_t)s_dst[el] * 40;
            const float* shp = s_sh[el];
            if (col < 8) {
                atomicAdd(op + col, gv);
            } else if (col < 12) {
                int m = col - 8;
#pragma unroll
                for (int t = 0; t < 3; ++t)
                    atomicAdd(op + 8 + m * 3 + t, gv * shp[1 + t]);
            } else {
                int m = col - 12;
#pragma unroll
                for (int t = 0; t < 5; ++t)
                    atomicAdd(op + 20 + m * 5 + t, gv * shp[4 + t]);
            }
        }
    }
}

// ---------------- finalize ----------------
__global__ __launch_bounds__(256) void finalize_kernel(
    float* __restrict__ out, const float* __restrict__ cnt, int total)
{
    int i = blockIdx.x * blockDim.x + threadIdx.x;
    if (i >= total) return;
    out[i] /= fmaxf(cnt[i / 40], 1.0f);
}

static inline size_t align256(size_t x) { return (x + 255) & ~(size_t)255; }

extern "C" void kernel_launch(void* const* d_in, const int* in_sizes, int n_in,
                              void* d_out, int out_size, void* d_ws, size_t ws_size,
                              hipStream_t stream)
{
    const float* pos         = (const float*)d_in[0];
    const float* edge_shifts = (const float*)d_in[1];
    const float* cell        = (const float*)d_in[2];
    const float* atom_table  = (const float*)d_in[3];
    const float* fw1 = (const float*)d_in[4];
    const float* fb1 = (const float*)d_in[5];
    const float* fw2 = (const float*)d_in[6];
    const float* fb2 = (const float*)d_in[7];
    const float* fw3 = (const float*)d_in[8];
    const float* fb3 = (const float*)d_in[9];
    const float* gw1 = (const float*)d_in[10];
    const float* gb1 = (const float*)d_in[11];
    const float* gw2 = (const float*)d_in[12];
    const float* gb2 = (const float*)d_in[13];
    const float* gw3 = (const float*)d_in[14];
    const float* gb3 = (const float*)d_in[15];
    const float* gw4 = (const float*)d_in[16];
    const float* gb4 = (const float*)d_in[17];
    const int* A        = (const int*)d_in[18];
    const int* batch    = (const int*)d_in[19];
    const int* edge_src = (const int*)d_in[20];
    const int* edge_dst = (const int*)d_in[21];

    int n_atoms = in_sizes[18];
    int n_edges = in_sizes[20];

    char* w = (char*)d_ws;
    float* Ai = (float*)w;                     w += align256((size_t)n_atoms * 8 * 4);
    float* cnt = (float*)w;                    w += align256((size_t)n_atoms * 4);
    unsigned short* h3g = (unsigned short*)w;  w += align256((size_t)n_edges * 64 * 2);
    unsigned short* W4pk = (unsigned short*)w; w += align256((size_t)65536 * 2);
    unsigned short* gw2T = (unsigned short*)w; w += align256((size_t)4096 * 2);
    unsigned short* gw3T = (unsigned short*)w; w += align256((size_t)4096 * 2);
    float* gb4pu = (float*)w;                  w += align256((size_t)1024 * 4);

    float* out = (float*)d_out;
    hipMemsetAsync(d_out, 0, sizeof(float) * (size_t)out_size, stream);
    hipMemsetAsync(cnt, 0, sizeof(float) * (size_t)n_atoms, stream);

    prep_kernel<<<(74752 + 255) / 256, 256, 0, stream>>>(
        gw4, gb4, gw2, gw3, W4pk, gw2T, gw3T, gb4pu);

    atoms_kernel<<<(n_atoms + 255) / 256, 256, 0, stream>>>(
        atom_table, A, fw1, fb1, fw2, fb2, fw3, fb3, Ai, n_atoms);

    edge_mlp_mfma<<<(n_edges + 63) / 64, 256, 0, stream>>>(
        pos, edge_shifts, cell, batch, edge_src, edge_dst,
        gw1, gb1, gb2, gb3, gw2T, gw3T, h3g, n_edges);

    edge_contract<<<(n_edges + 255) / 256, 256, 0, stream>>>(
        pos, edge_shifts, cell, batch, edge_src, edge_dst,
        Ai, h3g, W4pk, gb4pu, out, cnt, n_edges);

    int total = n_atoms * 40;
    finalize_kernel<<<(total + 255) / 256, 256, 0, stream>>>(out, cnt, total);
}

// Round 4
// 451.118 us; speedup vs baseline: 4.1584x; 1.3723x over previous
//
#include <hip/hip_runtime.h>
#include <math.h>

// N=25000, E=400000, S=8, NB=8, RMAX=5, EMB=16, MULS=(8,4,4), DIMS=(1,3,5), WNUM=1024
// g[e,u] = sum_p c[e,p] * ( sum_k h3[e,k] gw4[k, col(p,u)] + gb4[col(p,u)] )
// out[a, f(u,m)] = (1/cnt[a]) * sum_{e: dst=a} alpha * g[e,u] * sh[e, m]

typedef __attribute__((ext_vector_type(8))) short short8;
typedef __attribute__((ext_vector_type(4))) float f32x4;

__device__ __forceinline__ float silu_f(float x) { return x / (1.0f + __expf(-x)); }

__device__ __forceinline__ unsigned short bf16r(float f) {
    union { float f; unsigned u; } v; v.f = f;
    return (unsigned short)((v.u + 0x7fffu + ((v.u >> 16) & 1u)) >> 16);
}
__device__ __forceinline__ unsigned pack2(float lo, float hi) {
    return (unsigned)bf16r(lo) | ((unsigned)bf16r(hi) << 16);
}
__device__ __forceinline__ float bflo(unsigned u) {
    union { unsigned u; float f; } v; v.u = u << 16; return v.f;
}
__device__ __forceinline__ float bfhi(unsigned u) {
    union { unsigned u; float f; } v; v.u = u & 0xffff0000u; return v.f;
}
__device__ __forceinline__ int col_pu(int p, int u) {
    return (u < 8) ? (p * 8 + u)
         : (u < 12) ? (512 + p * 4 + (u - 8))
                    : (768 + p * 4 + (u - 12));
}

// ---------------- Atom MLP: 16 -> 64 -> 32 -> 8 ----------------
__global__ __launch_bounds__(256) void atoms_kernel(
    const float* __restrict__ atom_table, const int* __restrict__ A,
    const float* __restrict__ fw1, const float* __restrict__ fb1,
    const float* __restrict__ fw2, const float* __restrict__ fb2,
    const float* __restrict__ fw3, const float* __restrict__ fb3,
    float* __restrict__ Ai, int n_atoms)
{
    int n = blockIdx.x * blockDim.x + threadIdx.x;
    if (n >= n_atoms) return;
    const float* at = atom_table + A[n] * 16;

    float h1[64];
#pragma unroll
    for (int t = 0; t < 64; ++t) h1[t] = fb1[t];
#pragma unroll
    for (int k = 0; k < 16; ++k) {
        float x = at[k];
#pragma unroll
        for (int t = 0; t < 64; ++t) h1[t] += x * fw1[k * 64 + t];
    }
#pragma unroll
    for (int t = 0; t < 64; ++t) h1[t] = silu_f(h1[t]);

    float h2[32];
#pragma unroll
    for (int t = 0; t < 32; ++t) h2[t] = fb2[t];
#pragma unroll
    for (int k = 0; k < 64; ++k) {
        float x = h1[k];
#pragma unroll
        for (int t = 0; t < 32; ++t) h2[t] += x * fw2[k * 32 + t];
    }
#pragma unroll
    for (int t = 0; t < 32; ++t) h2[t] = silu_f(h2[t]);

    float o[8];
#pragma unroll
    for (int t = 0; t < 8; ++t) o[t] = fb3[t];
#pragma unroll
    for (int k = 0; k < 32; ++k) {
        float x = h2[k];
#pragma unroll
        for (int t = 0; t < 8; ++t) o[t] += x * fw3[k * 8 + t];
    }
#pragma unroll
    for (int t = 0; t < 8; ++t) Ai[n * 8 + t] = o[t];
}

// ---------------- prep: W4pk[p][u][k], gw1Tp[n][k32], gw2T/gw3T[n][k], gb4pu ------
__global__ __launch_bounds__(256) void prep_kernel(
    const float* __restrict__ gw4, const float* __restrict__ gb4,
    const float* __restrict__ gw1, const float* __restrict__ gw2,
    const float* __restrict__ gw3,
    unsigned short* __restrict__ W4pk, unsigned short* __restrict__ gw1Tp,
    unsigned short* __restrict__ gw2T, unsigned short* __restrict__ gw3T,
    float* __restrict__ gb4pu)
{
    int idx = blockIdx.x * 256 + threadIdx.x;
    if (idx < 65536) {
        int p = idx >> 10, u = (idx >> 6) & 15, k = idx & 63;
        W4pk[idx] = bf16r(gw4[k * 1024 + col_pu(p, u)]);
    } else if (idx < 67584) {
        int t = idx - 65536; int n = t >> 5, k = t & 31;
        gw1Tp[t] = (k < 8) ? bf16r(gw1[k * 64 + n]) : (unsigned short)0;
    } else if (idx < 71680) {
        int t = idx - 67584; int n = t >> 6, k = t & 63;
        gw2T[t] = bf16r(gw2[k * 64 + n]);
    } else if (idx < 75776) {
        int t = idx - 71680; int n = t >> 6, k = t & 63;
        gw3T[t] = bf16r(gw3[k * 64 + n]);
    } else if (idx < 76800) {
        int t = idx - 75776; int p = t >> 4, u = t & 15;
        gb4pu[t] = gb4[col_pu(p, u)];
    }
}

// ---------------- CSR build ----------------
__global__ __launch_bounds__(256) void hist_kernel(
    const int* __restrict__ edge_dst, int* __restrict__ cnt, int n_edges)
{
    int e = blockIdx.x * 256 + threadIdx.x;
    if (e < n_edges) atomicAdd(&cnt[edge_dst[e]], 1);
}

__global__ __launch_bounds__(1024) void scan_kernel(
    const int* __restrict__ cnt, int* __restrict__ off, int* __restrict__ cur, int n)
{
    __shared__ int s[1024];
    int tid = threadIdx.x;
    int chunk = (n + 1023) / 1024;
    int start = tid * chunk;
    int end = min(start + chunk, n);
    int sum = 0;
    for (int i = start; i < end; ++i) sum += cnt[i];
    s[tid] = sum;
    __syncthreads();
    for (int d = 1; d < 1024; d <<= 1) {
        int v = (tid >= d) ? s[tid - d] : 0;
        __syncthreads();
        s[tid] += v;
        __syncthreads();
    }
    int run = (tid == 0) ? 0 : s[tid - 1];
    for (int i = start; i < end; ++i) {
        off[i] = run; cur[i] = run; run += cnt[i];
    }
    if (tid == 1023) off[n] = s[1023];
}

__global__ __launch_bounds__(256) void scatter_kernel(
    const int* __restrict__ edge_dst, int* __restrict__ cur,
    int* __restrict__ eidx, int n_edges)
{
    int e = blockIdx.x * 256 + threadIdx.x;
    if (e < n_edges) {
        int slot = atomicAdd(&cur[edge_dst[e]], 1);
        eidx[slot] = e;
    }
}

// ---------------- radial MLP via MFMA: emb(8,K-pad 32) ->64 ->64 ->64 -----------
// block = 256 (4 waves), 256 edges/block, 64 edges/wave (4 subtiles of 16).
__global__ __launch_bounds__(256) void edge_mlp_mfma(
    const float* __restrict__ pos, const float* __restrict__ edge_shifts,
    const float* __restrict__ cell, const int* __restrict__ batch,
    const int* __restrict__ edge_src, const int* __restrict__ edge_dst,
    const float* __restrict__ gb1, const float* __restrict__ gb2,
    const float* __restrict__ gb3,
    const unsigned short* __restrict__ gw1Tp, const unsigned short* __restrict__ gw2T,
    const unsigned short* __restrict__ gw3T,
    unsigned short* __restrict__ h3g, int n_edges)
{
    __shared__ unsigned short s_emb[256][8];      // 4 KB
    __shared__ unsigned short s_h[4][64][72];     // 36 KB, per-wave h buffer

    int tid = threadIdx.x;
    int eb = blockIdx.x * 256;

    {   // phase 0: one edge per thread — radial embedding
        int ec = min(eb + tid, n_edges - 1);
        int src = edge_src[ec], dst = edge_dst[ec];
        int b = batch[src];
        const float* C = cell + b * 9;
        float es0 = edge_shifts[ec * 3 + 0];
        float es1 = edge_shifts[ec * 3 + 1];
        float es2 = edge_shifts[ec * 3 + 2];
        float vx = pos[dst * 3 + 0] - pos[src * 3 + 0] + es0 * C[0] + es1 * C[3] + es2 * C[6];
        float vy = pos[dst * 3 + 1] - pos[src * 3 + 1] + es0 * C[1] + es1 * C[4] + es2 * C[7];
        float vz = pos[dst * 3 + 2] - pos[src * 3 + 2] + es0 * C[2] + es1 * C[5] + es2 * C[8];
        float r = sqrtf(vx * vx + vy * vy + vz * vz + 1e-12f);
        float xr = fminf(r * 0.2f, 1.0f);
        float cutoff = (r <= 5.0f) ? 2.8284271247461903f : 0.0f;
        float em[8];
#pragma unroll
        for (int k = 0; k < 8; ++k) {
            float d = (xr - (float)k * (1.0f / 7.0f)) * 7.0f;
            em[k] = __expf(-0.5f * d * d) * cutoff;
        }
        *(uint4*)&s_emb[tid][0] = make_uint4(pack2(em[0], em[1]), pack2(em[2], em[3]),
                                             pack2(em[4], em[5]), pack2(em[6], em[7]));
    }
    __syncthreads();

    int w = tid >> 6, lane = tid & 63, quad = lane >> 4, col = lane & 15;

    // ---- layer 1: A = emb (k<8 real, rest zero), B = gw1Tp[n][k32]
#pragma unroll
    for (int s = 0; s < 4; ++s) {
        short8 a = *(const short8*)&s_emb[w * 64 + s * 16 + col][0];
        if (quad != 0) {
            short8 z = {0, 0, 0, 0, 0, 0, 0, 0};
            a = z;
        }
#pragma unroll
        for (int nt = 0; nt < 4; ++nt) {
            int n = nt * 16 + col;
            short8 b = *(const short8*)(gw1Tp + n * 32 + quad * 8);
            float bb = gb1[n];
            f32x4 d = {bb, bb, bb, bb};
            d = __builtin_amdgcn_mfma_f32_16x16x32_bf16(a, b, d, 0, 0, 0);
#pragma unroll
            for (int r = 0; r < 4; ++r)
                s_h[w][s * 16 + quad * 4 + r][n] = bf16r(silu_f(d[r]));
        }
    }

    // ---- layers 2 and 3 (MFMA)
#pragma unroll 1
    for (int layer = 0; layer < 2; ++layer) {
        const unsigned short* WT = layer ? gw3T : gw2T;
        const float* gb = layer ? gb3 : gb2;

        __syncthreads();
        short8 a0[4], a1[4];
#pragma unroll
        for (int s = 0; s < 4; ++s) {
            a0[s] = *(const short8*)&s_h[w][s * 16 + col][quad * 8];
            a1[s] = *(const short8*)&s_h[w][s * 16 + col][32 + quad * 8];
        }
        __syncthreads();   // reads done before overwrites

#pragma unroll
        for (int nt = 0; nt < 4; ++nt) {
            int n = nt * 16 + col;
            short8 b0 = *(const short8*)(WT + n * 64 + quad * 8);
            short8 b1 = *(const short8*)(WT + n * 64 + 32 + quad * 8);
            float bb = gb[n];
#pragma unroll
            for (int s = 0; s < 4; ++s) {
                f32x4 d = {bb, bb, bb, bb};
                d = __builtin_amdgcn_mfma_f32_16x16x32_bf16(a0[s], b0, d, 0, 0, 0);
                d = __builtin_amdgcn_mfma_f32_16x16x32_bf16(a1[s], b1, d, 0, 0, 0);
#pragma unroll
                for (int r = 0; r < 4; ++r)
                    s_h[w][s * 16 + quad * 4 + r][n] = bf16r(silu_f(d[r]));
            }
        }
    }
    __syncthreads();

    // ---- h3 writeout (coalesced 32 B/lane per chunk)
#pragma unroll
    for (int ch = 0; ch < 4; ++ch) {
        int elw = ch * 16 + (lane >> 2), seg = lane & 3;
        const uint4* sp = (const uint4*)&s_h[w][elw][seg * 16];
        uint4 v0 = sp[0], v1 = sp[1];
        int ge = min(eb + w * 64 + elw, n_edges - 1);
        uint4* dp = (uint4*)(h3g + (size_t)ge * 64 + seg * 16);
        dp[0] = v0; dp[1] = v1;
    }
}

// ---------------- contraction -> per-edge rows ----------------
// block = 256 (4 waves), 256 edges/block, 64 edges/wave.
// erow (f32[32] per edge) ALIASES h3g (u16[64] per edge, both 128 B):
// each block overwrites only its own edges' rows, after a __syncthreads that
// guarantees all its h3 A-fragment loads completed.
__global__ __launch_bounds__(256) void edge_contract(
    const float* __restrict__ pos, const float* __restrict__ edge_shifts,
    const float* __restrict__ cell, const int* __restrict__ batch,
    const int* __restrict__ edge_src, const int* __restrict__ edge_dst,
    const float* __restrict__ Ai, const unsigned short* __restrict__ h3g,
    const unsigned short* __restrict__ W4pk, const float* __restrict__ gb4pu,
    float* __restrict__ erowf, int n_edges)
{
    __shared__ float s_sh[256][12];           // 12 KB
    __shared__ unsigned short s_c[64][264];   // 33 KB, [p][e] bf16

    int tid = threadIdx.x;
    int eb = blockIdx.x * 256;

    {   // phase 0: one edge per thread — geometry + sh + c column
        int ec = min(eb + tid, n_edges - 1);
        int src = edge_src[ec], dst = edge_dst[ec];
        int b = batch[src];
        const float* C = cell + b * 9;
        float es0 = edge_shifts[ec * 3 + 0];
        float es1 = edge_shifts[ec * 3 + 1];
        float es2 = edge_shifts[ec * 3 + 2];
        float vx = pos[dst * 3 + 0] - pos[src * 3 + 0] + es0 * C[0] + es1 * C[3] + es2 * C[6];
        float vy = pos[dst * 3 + 1] - pos[src * 3 + 1] + es0 * C[1] + es1 * C[4] + es2 * C[7];
        float vz = pos[dst * 3 + 2] - pos[src * 3 + 2] + es0 * C[2] + es1 * C[5] + es2 * C[8];
        float inv = rsqrtf(vx * vx + vy * vy + vz * vz + 1e-12f);
        float x = vx * inv, y = vy * inv, z = vz * inv;
        const float s3 = 1.7320508075688772f;
        const float s5 = 2.23606797749979f;
        const float s15 = 3.872983346207417f;
        s_sh[tid][0] = 1.0f;
        s_sh[tid][1] = s3 * x; s_sh[tid][2] = s3 * y; s_sh[tid][3] = s3 * z;
        s_sh[tid][4] = s15 * x * y;
        s_sh[tid][5] = s15 * y * z;
        s_sh[tid][6] = 0.5f * s5 * (2.0f * z * z - x * x - y * y);
        s_sh[tid][7] = s15 * x * z;
        s_sh[tid][8] = 0.5f * s15 * (x * x - y * y);

        const float4* asp = (const float4*)(Ai + (size_t)src * 8);
        float4 A0 = asp[0], A1 = asp[1];
        const float4* adp = (const float4*)(Ai + (size_t)dst * 8);
        float4 B0 = adp[0], B1 = adp[1];
        float as[8] = {A0.x, A0.y, A0.z, A0.w, A1.x, A1.y, A1.z, A1.w};
        float ad[8] = {B0.x, B0.y, B0.z, B0.w, B1.x, B1.y, B1.z, B1.w};
#pragma unroll
        for (int p = 0; p < 64; ++p)
            s_c[p][tid] = bf16r(as[p >> 3] * ad[p & 7]);
    }

    // A-frags: h3, straight from global
    int w = tid >> 6, lane = tid & 63, quad = lane >> 4, col = lane & 15;
    short8 aH0[4], aH1[4];
#pragma unroll
    for (int s = 0; s < 4; ++s) {
        int ge = min(eb + w * 64 + s * 16 + col, n_edges - 1);
        const unsigned short* hp = h3g + (size_t)ge * 64 + quad * 8;
        aH0[s] = *(const short8*)hp;
        aH1[s] = *(const short8*)(hp + 32);
    }
    __syncthreads();

    f32x4 g[4];
#pragma unroll
    for (int s = 0; s < 4; ++s) g[s] = (f32x4){0.0f, 0.0f, 0.0f, 0.0f};

    const unsigned short* wb = W4pk + col * 64 + quad * 8;
    const char* cbase = (const char*)s_c + w * 128 + quad * 8;

#pragma unroll 2
    for (int p = 0; p < 64; ++p) {
        short8 b0 = *(const short8*)(wb + p * 1024);
        short8 b1 = *(const short8*)(wb + p * 1024 + 32);
        float bb = gb4pu[p * 16 + col];
        f32x4 binit = {bb, bb, bb, bb};
        const char* crow = cbase + p * 528;
#pragma unroll
        for (int s = 0; s < 4; ++s) {
            f32x4 d = binit;
            d = __builtin_amdgcn_mfma_f32_16x16x32_bf16(aH0[s], b0, d, 0, 0, 0);
            d = __builtin_amdgcn_mfma_f32_16x16x32_bf16(aH1[s], b1, d, 0, 0, 0);
            uint2 cc = *(const uint2*)(crow + s * 32);
            g[s].x += bflo(cc.x) * d.x;
            g[s].y += bfhi(cc.x) * d.y;
            g[s].z += bflo(cc.y) * d.z;
            g[s].w += bfhi(cc.y) * d.w;
        }
    }
    __syncthreads();   // all h3 loads done block-wide -> safe to overwrite rows

    // epilogue: write per-edge rows [g*alpha (16), sh (9)]
    const float alpha = 0.125f;
#pragma unroll
    for (int s = 0; s < 4; ++s) {
        float garr[4] = {g[s].x, g[s].y, g[s].z, g[s].w};
#pragma unroll
        for (int r = 0; r < 4; ++r) {
            int el = w * 64 + s * 16 + quad * 4 + r;
            int ge = eb + el;
            if (ge < n_edges) {
                erowf[(size_t)ge * 32 + col] = alpha * garr[r];
                if (col < 9)
                    erowf[(size_t)ge * 32 + 16 + col] = s_sh[el][col];
            }
        }
    }
}

// ---------------- gather: wave per atom, lane per feature ----------------
__global__ __launch_bounds__(256) void gather_kernel(
    const int* __restrict__ off, const int* __restrict__ eidx,
    const float* __restrict__ erowf, float* __restrict__ out, int n_atoms)
{
    int w = threadIdx.x >> 6, lane = threadIdx.x & 63;
    int a = blockIdx.x * 4 + w;
    if (a >= n_atoms) return;
    int beg = off[a], end = off[a + 1];

    int f = min(lane, 39);
    int u, shi;
    if (f < 8)       { u = f;                shi = 0; }
    else if (f < 20) { u = 8 + (f - 8) / 3;  shi = 1 + (f - 8) % 3; }
    else             { u = 12 + (f - 20) / 5; shi = 4 + (f - 20) % 5; }

    float val = 0.0f;
    for (int i = beg; i < end; ++i) {
        int e = eidx[i];
        const float* rp = erowf + (size_t)e * 32;
        val += rp[u] * rp[16 + shi];
    }
    if (lane < 40) {
        float c = (float)max(end - beg, 1);
        out[(size_t)a * 40 + lane] = val / c;
    }
}

static inline size_t align256(size_t x) { return (x + 255) & ~(size_t)255; }

extern "C" void kernel_launch(void* const* d_in, const int* in_sizes, int n_in,
                              void* d_out, int out_size, void* d_ws, size_t ws_size,
                              hipStream_t stream)
{
    const float* pos         = (const float*)d_in[0];
    const float* edge_shifts = (const float*)d_in[1];
    const float* cell        = (const float*)d_in[2];
    const float* atom_table  = (const float*)d_in[3];
    const float* fw1 = (const float*)d_in[4];
    const float* fb1 = (const float*)d_in[5];
    const float* fw2 = (const float*)d_in[6];
    const float* fb2 = (const float*)d_in[7];
    const float* fw3 = (const float*)d_in[8];
    const float* fb3 = (const float*)d_in[9];
    const float* gw1 = (const float*)d_in[10];
    const float* gb1 = (const float*)d_in[11];
    const float* gw2 = (const float*)d_in[12];
    const float* gb2 = (const float*)d_in[13];
    const float* gw3 = (const float*)d_in[14];
    const float* gb3 = (const float*)d_in[15];
    const float* gw4 = (const float*)d_in[16];
    const float* gb4 = (const float*)d_in[17];
    const int* A        = (const int*)d_in[18];
    const int* batch    = (const int*)d_in[19];
    const int* edge_src = (const int*)d_in[20];
    const int* edge_dst = (const int*)d_in[21];

    int n_atoms = in_sizes[18];
    int n_edges = in_sizes[20];

    char* w = (char*)d_ws;
    float* Ai = (float*)w;                     w += align256((size_t)n_atoms * 8 * 4);
    int* cnt_i = (int*)w;                      w += align256((size_t)n_atoms * 4);
    int* off = (int*)w;                        w += align256((size_t)(n_atoms + 1) * 4);
    int* cur = (int*)w;                        w += align256((size_t)n_atoms * 4);
    int* eidx = (int*)w;                       w += align256((size_t)n_edges * 4);
    unsigned short* h3g = (unsigned short*)w;  w += align256((size_t)n_edges * 64 * 2);
    unsigned short* W4pk = (unsigned short*)w; w += align256((size_t)65536 * 2);
    unsigned short* gw1Tp = (unsigned short*)w; w += align256((size_t)2048 * 2);
    unsigned short* gw2T = (unsigned short*)w; w += align256((size_t)4096 * 2);
    unsigned short* gw3T = (unsigned short*)w; w += align256((size_t)4096 * 2);
    float* gb4pu = (float*)w;                  w += align256((size_t)1024 * 4);

    float* erowf = (float*)h3g;   // aliased on purpose (see edge_contract)
    float* out = (float*)d_out;

    hipMemsetAsync(cnt_i, 0, sizeof(int) * (size_t)n_atoms, stream);

    prep_kernel<<<(76800 + 255) / 256, 256, 0, stream>>>(
        gw4, gb4, gw1, gw2, gw3, W4pk, gw1Tp, gw2T, gw3T, gb4pu);

    atoms_kernel<<<(n_atoms + 255) / 256, 256, 0, stream>>>(
        atom_table, A, fw1, fb1, fw2, fb2, fw3, fb3, Ai, n_atoms);

    hist_kernel<<<(n_edges + 255) / 256, 256, 0, stream>>>(edge_dst, cnt_i, n_edges);
    scan_kernel<<<1, 1024, 0, stream>>>(cnt_i, off, cur, n_atoms);
    scatter_kernel<<<(n_edges + 255) / 256, 256, 0, stream>>>(edge_dst, cur, eidx, n_edges);

    edge_mlp_mfma<<<(n_edges + 255) / 256, 256, 0, stream>>>(
        pos, edge_shifts, cell, batch, edge_src, edge_dst,
        gb1, gb2, gb3, gw1Tp, gw2T, gw3T, h3g, n_edges);

    edge_contract<<<(n_edges + 255) / 256, 256, 0, stream>>>(
        pos, edge_shifts, cell, batch, edge_src, edge_dst,
        Ai, h3g, W4pk, gb4pu, erowf, n_edges);

    gather_kernel<<<(n_atoms + 3) / 4, 256, 0, stream>>>(off, eidx, erowf, out, n_atoms);
}

// Round 5
// 397.346 us; speedup vs baseline: 4.7211x; 1.1353x over previous
//
#include <hip/hip_runtime.h>
#include <hip/hip_bf16.h>
#include <math.h>

// N=25000, E=400000, S=8, NB=8, RMAX=5, EMB=16, MULS=(8,4,4), DIMS=(1,3,5), WNUM=1024
// g[e,u] = sum_p c[e,p] * ( sum_k h3[e,k] gw4[k, col(p,u)] + gb4[col(p,u)] )
// out[a, f(u,m)] = (1/cnt[a]) * sum_{e: dst=a} alpha * g[e,u] * sh[e, m]

typedef __attribute__((ext_vector_type(8))) short short8;
typedef __attribute__((ext_vector_type(4))) float f32x4;

__device__ __forceinline__ float silu_f(float x) { return x / (1.0f + __expf(-x)); }

__device__ __forceinline__ unsigned short bf16r(float f) {
    union { float f; unsigned u; } v; v.f = f;
    return (unsigned short)((v.u + 0x7fffu + ((v.u >> 16) & 1u)) >> 16);
}
__device__ __forceinline__ unsigned pkcvt(float lo, float hi) {
    union { __hip_bfloat162 h; unsigned u; } v;
    v.h = __float22bfloat162_rn(float2{lo, hi});
    return v.u;
}
__device__ __forceinline__ float bflo(unsigned u) {
    union { unsigned u; float f; } v; v.u = u << 16; return v.f;
}
__device__ __forceinline__ float bfhi(unsigned u) {
    union { unsigned u; float f; } v; v.u = u & 0xffff0000u; return v.f;
}
__device__ __forceinline__ int col_pu(int p, int u) {
    return (u < 8) ? (p * 8 + u)
         : (u < 12) ? (512 + p * 4 + (u - 8))
                    : (768 + p * 4 + (u - 12));
}

// ---------------- Atom MLP: 16 -> 64 -> 32 -> 8 ----------------
__global__ __launch_bounds__(256) void atoms_kernel(
    const float* __restrict__ atom_table, const int* __restrict__ A,
    const float* __restrict__ fw1, const float* __restrict__ fb1,
    const float* __restrict__ fw2, const float* __restrict__ fb2,
    const float* __restrict__ fw3, const float* __restrict__ fb3,
    float* __restrict__ Ai, int n_atoms)
{
    int n = blockIdx.x * blockDim.x + threadIdx.x;
    if (n >= n_atoms) return;
    const float* at = atom_table + A[n] * 16;

    float h1[64];
#pragma unroll
    for (int t = 0; t < 64; ++t) h1[t] = fb1[t];
#pragma unroll
    for (int k = 0; k < 16; ++k) {
        float x = at[k];
#pragma unroll
        for (int t = 0; t < 64; ++t) h1[t] += x * fw1[k * 64 + t];
    }
#pragma unroll
    for (int t = 0; t < 64; ++t) h1[t] = silu_f(h1[t]);

    float h2[32];
#pragma unroll
    for (int t = 0; t < 32; ++t) h2[t] = fb2[t];
#pragma unroll
    for (int k = 0; k < 64; ++k) {
        float x = h1[k];
#pragma unroll
        for (int t = 0; t < 32; ++t) h2[t] += x * fw2[k * 32 + t];
    }
#pragma unroll
    for (int t = 0; t < 32; ++t) h2[t] = silu_f(h2[t]);

    float o[8];
#pragma unroll
    for (int t = 0; t < 8; ++t) o[t] = fb3[t];
#pragma unroll
    for (int k = 0; k < 32; ++k) {
        float x = h2[k];
#pragma unroll
        for (int t = 0; t < 8; ++t) o[t] += x * fw3[k * 8 + t];
    }
#pragma unroll
    for (int t = 0; t < 8; ++t) Ai[n * 8 + t] = o[t];
}

// ---------------- prep ----------------
__global__ __launch_bounds__(256) void prep_kernel(
    const float* __restrict__ gw4, const float* __restrict__ gb4,
    const float* __restrict__ gw1, const float* __restrict__ gw2,
    const float* __restrict__ gw3,
    unsigned short* __restrict__ W4pk, unsigned short* __restrict__ gw1Tp,
    unsigned short* __restrict__ gw2T, unsigned short* __restrict__ gw3T,
    unsigned short* __restrict__ gb4T2)
{
    int idx = blockIdx.x * 256 + threadIdx.x;
    if (idx < 65536) {
        int p = idx >> 10, u = (idx >> 6) & 15, k = idx & 63;
        W4pk[idx] = bf16r(gw4[k * 1024 + col_pu(p, u)]);
    } else if (idx < 67584) {
        int t = idx - 65536; int n = t >> 5, k = t & 31;
        gw1Tp[t] = (k < 8) ? bf16r(gw1[k * 64 + n]) : (unsigned short)0;
    } else if (idx < 71680) {
        int t = idx - 67584; int n = t >> 6, k = t & 63;
        gw2T[t] = bf16r(gw2[k * 64 + n]);
    } else if (idx < 75776) {
        int t = idx - 71680; int n = t >> 6, k = t & 63;
        gw3T[t] = bf16r(gw3[k * 64 + n]);
    } else if (idx < 76800) {
        int t = idx - 75776; int u = t >> 6, p = t & 63;
        gb4T2[t] = bf16r(gb4[col_pu(p, u)]);
    }
}

// ---------------- CSR build ----------------
__global__ __launch_bounds__(256) void hist_kernel(
    const int* __restrict__ edge_dst, int* __restrict__ cnt, int n_edges)
{
    int e = blockIdx.x * 256 + threadIdx.x;
    if (e < n_edges) atomicAdd(&cnt[edge_dst[e]], 1);
}

__global__ __launch_bounds__(1024) void scan_kernel(
    const int* __restrict__ cnt, int* __restrict__ off, int* __restrict__ cur, int n)
{
    __shared__ int s[1024];
    int tid = threadIdx.x;
    int chunk = (n + 1023) / 1024;
    int start = tid * chunk;
    int end = min(start + chunk, n);
    int sum = 0;
    for (int i = start; i < end; ++i) sum += cnt[i];
    s[tid] = sum;
    __syncthreads();
    for (int d = 1; d < 1024; d <<= 1) {
        int v = (tid >= d) ? s[tid - d] : 0;
        __syncthreads();
        s[tid] += v;
        __syncthreads();
    }
    int run = (tid == 0) ? 0 : s[tid - 1];
    for (int i = start; i < end; ++i) {
        off[i] = run; cur[i] = run; run += cnt[i];
    }
    if (tid == 1023) off[n] = s[1023];
}

__global__ __launch_bounds__(256) void scatter_kernel(
    const int* __restrict__ edge_dst, int* __restrict__ cur,
    int* __restrict__ rank, int n_edges)
{
    int e = blockIdx.x * 256 + threadIdx.x;
    if (e < n_edges) {
        int slot = atomicAdd(&cur[edge_dst[e]], 1);
        rank[e] = slot;
    }
}

// ---------------- fused edge kernel ----------------
// block = 256 (4 waves), 256 edges/block, 64 edges/wave (4 subtiles of 16).
// Phase A: radial MLP (MFMA) emb(8,Kpad32)->64->64->64 in LDS.
// Phase B: g[e,u] = bias-GEMM(c,gb4T2) + sum_p c[e,p]*MFMA(h3, W4pk[p]).
// Output rows written CSR-ordered via rank[] -> gather reads sequentially.
__global__ __launch_bounds__(256, 3) void edge_fused(
    const float* __restrict__ pos, const float* __restrict__ edge_shifts,
    const float* __restrict__ cell, const int* __restrict__ batch,
    const int* __restrict__ edge_src, const int* __restrict__ edge_dst,
    const float* __restrict__ Ai,
    const float* __restrict__ gb1, const float* __restrict__ gb2,
    const float* __restrict__ gb3,
    const unsigned short* __restrict__ gw1Tp, const unsigned short* __restrict__ gw2T,
    const unsigned short* __restrict__ gw3T,
    const unsigned short* __restrict__ W4pk, const unsigned short* __restrict__ gb4T2,
    const int* __restrict__ rank, float* __restrict__ erow, int n_edges)
{
    // union'd LDS: phase A = s_emb(4K) + s_h(36K); phase B = s_c2(33K) + s_rank(1K)
    __shared__ __align__(16) char smem[40960];
    unsigned short (*s_emb)[8] = (unsigned short(*)[8])smem;
    typedef unsigned short hrow_t[64][72];
    hrow_t* s_hh = (hrow_t*)(smem + 4096);

    int tid = threadIdx.x;
    int eb = blockIdx.x * 256;
    int w = tid >> 6, lane = tid & 63, quad = lane >> 4, col = lane & 15;

    int ec = min(eb + tid, n_edges - 1);
    int src = edge_src[ec], dst = edge_dst[ec];
    int rk = rank[ec];

    {   // phase 0: geometry -> emb (LDS) + sh (straight to erow row)
        int b = batch[src];
        const float* C = cell + b * 9;
        float es0 = edge_shifts[ec * 3 + 0];
        float es1 = edge_shifts[ec * 3 + 1];
        float es2 = edge_shifts[ec * 3 + 2];
        float vx = pos[dst * 3 + 0] - pos[src * 3 + 0] + es0 * C[0] + es1 * C[3] + es2 * C[6];
        float vy = pos[dst * 3 + 1] - pos[src * 3 + 1] + es0 * C[1] + es1 * C[4] + es2 * C[7];
        float vz = pos[dst * 3 + 2] - pos[src * 3 + 2] + es0 * C[2] + es1 * C[5] + es2 * C[8];
        float r2 = vx * vx + vy * vy + vz * vz + 1e-12f;
        float r = sqrtf(r2);
        float inv = 1.0f / r;
        float x = vx * inv, y = vy * inv, z = vz * inv;

        float xr = fminf(r * 0.2f, 1.0f);
        float cutoff = (r <= 5.0f) ? 2.8284271247461903f : 0.0f;
        float em[8];
#pragma unroll
        for (int k = 0; k < 8; ++k) {
            float d = (xr - (float)k * (1.0f / 7.0f)) * 7.0f;
            em[k] = __expf(-0.5f * d * d) * cutoff;
        }
        *(uint4*)&s_emb[tid][0] = make_uint4(pkcvt(em[0], em[1]), pkcvt(em[2], em[3]),
                                             pkcvt(em[4], em[5]), pkcvt(em[6], em[7]));

        const float s3 = 1.7320508075688772f;
        const float s5 = 2.23606797749979f;
        const float s15 = 3.872983346207417f;
        float* op = erow + (size_t)rk * 32 + 16;
        op[0] = 1.0f;
        op[1] = s3 * x; op[2] = s3 * y; op[3] = s3 * z;
        op[4] = s15 * x * y;
        op[5] = s15 * y * z;
        op[6] = 0.5f * s5 * (2.0f * z * z - x * x - y * y);
        op[7] = s15 * x * z;
        op[8] = 0.5f * s15 * (x * x - y * y);
    }
    __syncthreads();

    // ---- phase A, layer 1: A = emb (k<8), B = gw1Tp[n][k32]
#pragma unroll
    for (int s = 0; s < 4; ++s) {
        short8 a = *(const short8*)&s_emb[w * 64 + s * 16 + col][0];
        if (quad != 0) {
            short8 z = {0, 0, 0, 0, 0, 0, 0, 0};
            a = z;
        }
#pragma unroll
        for (int nt = 0; nt < 4; ++nt) {
            int n = nt * 16 + col;
            short8 b = *(const short8*)(gw1Tp + n * 32 + quad * 8);
            float bb = gb1[n];
            f32x4 d = {bb, bb, bb, bb};
            d = __builtin_amdgcn_mfma_f32_16x16x32_bf16(a, b, d, 0, 0, 0);
#pragma unroll
            for (int r = 0; r < 4; ++r)
                s_hh[w][s * 16 + quad * 4 + r][n] = bf16r(silu_f(d[r]));
        }
    }

    // ---- phase A, layers 2 and 3
#pragma unroll 1
    for (int layer = 0; layer < 2; ++layer) {
        const unsigned short* WT = layer ? gw3T : gw2T;
        const float* gb = layer ? gb3 : gb2;

        __syncthreads();
        short8 a0[4], a1[4];
#pragma unroll
        for (int s = 0; s < 4; ++s) {
            a0[s] = *(const short8*)&s_hh[w][s * 16 + col][quad * 8];
            a1[s] = *(const short8*)&s_hh[w][s * 16 + col][32 + quad * 8];
        }
        __syncthreads();

#pragma unroll
        for (int nt = 0; nt < 4; ++nt) {
            int n = nt * 16 + col;
            short8 b0 = *(const short8*)(WT + n * 64 + quad * 8);
            short8 b1 = *(const short8*)(WT + n * 64 + 32 + quad * 8);
            float bb = gb[n];
#pragma unroll
            for (int s = 0; s < 4; ++s) {
                f32x4 d = {bb, bb, bb, bb};
                d = __builtin_amdgcn_mfma_f32_16x16x32_bf16(a0[s], b0, d, 0, 0, 0);
                d = __builtin_amdgcn_mfma_f32_16x16x32_bf16(a1[s], b1, d, 0, 0, 0);
#pragma unroll
                for (int r = 0; r < 4; ++r)
                    s_hh[w][s * 16 + quad * 4 + r][n] = bf16r(silu_f(d[r]));
            }
        }
    }
    __syncthreads();

    // ---- h3 A-frags to registers, then phase-B LDS may overwrite
    short8 aH0[4], aH1[4];
#pragma unroll
    for (int s = 0; s < 4; ++s) {
        aH0[s] = *(const short8*)&s_hh[w][s * 16 + col][quad * 8];
        aH1[s] = *(const short8*)&s_hh[w][s * 16 + col][32 + quad * 8];
    }
    __syncthreads();

    // ---- phase B prep: pair-packed c[pp][e] bf16x2 + rank cache
    unsigned* s_c2 = (unsigned*)smem;            // [32][264]
    int* s_rank = (int*)(smem + 33792);
    s_rank[tid] = rk;
    {
        const float4* asp = (const float4*)(Ai + (size_t)src * 8);
        float4 A0 = asp[0], A1 = asp[1];
        const float4* adp = (const float4*)(Ai + (size_t)dst * 8);
        float4 B0 = adp[0], B1 = adp[1];
        float as[8] = {A0.x, A0.y, A0.z, A0.w, A1.x, A1.y, A1.z, A1.w};
        float ad[8] = {B0.x, B0.y, B0.z, B0.w, B1.x, B1.y, B1.z, B1.w};
#pragma unroll
        for (int pp = 0; pp < 32; ++pp) {
            int p = pp * 2;
            float av = as[p >> 3];
            s_c2[pp * 264 + tid] = pkcvt(av * ad[p & 7], av * ad[(p & 7) + 1]);
        }
    }
    __syncthreads();

    // ---- bias GEMM: g = c @ gb4T2^T  (A from s_c2, K=64)
    f32x4 g[4];
    {
        const unsigned short* bbp = gb4T2 + col * 64 + quad * 8;
        short8 b0 = *(const short8*)bbp;
        short8 b1 = *(const short8*)(bbp + 32);
        f32x4 zero4 = {0.0f, 0.0f, 0.0f, 0.0f};
#pragma unroll
        for (int s = 0; s < 4; ++s) {
            int ebase = w * 64 + s * 16 + col;
            unsigned dw0[4], dw1[4];
#pragma unroll
            for (int t = 0; t < 4; ++t) dw0[t] = s_c2[(quad * 4 + t) * 264 + ebase];
#pragma unroll
            for (int t = 0; t < 4; ++t) dw1[t] = s_c2[(16 + quad * 4 + t) * 264 + ebase];
            union { unsigned u[4]; short8 s8; } ua, ub;
#pragma unroll
            for (int t = 0; t < 4; ++t) { ua.u[t] = dw0[t]; ub.u[t] = dw1[t]; }
            f32x4 d = __builtin_amdgcn_mfma_f32_16x16x32_bf16(ua.s8, b0, zero4, 0, 0, 0);
            g[s] = __builtin_amdgcn_mfma_f32_16x16x32_bf16(ub.s8, b1, d, 0, 0, 0);
        }
    }

    // ---- main p-loop (pairs, 1-pair-ahead B prefetch; OOB prefetch lands in gw1Tp)
    const unsigned short* wb = W4pk + col * 64 + quad * 8;
    const char* cbase = (const char*)s_c2 + w * 256 + quad * 16;
    f32x4 zero4 = {0.0f, 0.0f, 0.0f, 0.0f};

    short8 pb0 = *(const short8*)(wb);
    short8 pb1 = *(const short8*)(wb + 32);
    short8 qb0 = *(const short8*)(wb + 1024);
    short8 qb1 = *(const short8*)(wb + 1056);

#pragma unroll 2
    for (int pp = 0; pp < 32; ++pp) {
        short8 b0 = pb0, b1 = pb1, e0 = qb0, e1 = qb1;
        const unsigned short* nw = wb + (2 * pp + 2) * 1024;
        pb0 = *(const short8*)(nw);
        pb1 = *(const short8*)(nw + 32);
        qb0 = *(const short8*)(nw + 1024);
        qb1 = *(const short8*)(nw + 1056);

        uint4 cc[4];
#pragma unroll
        for (int s = 0; s < 4; ++s)
            cc[s] = *(const uint4*)(cbase + pp * 1056 + s * 64);

        f32x4 d[4], d2[4];
#pragma unroll
        for (int s = 0; s < 4; ++s) {
            f32x4 t = __builtin_amdgcn_mfma_f32_16x16x32_bf16(aH0[s], b0, zero4, 0, 0, 0);
            d[s] = __builtin_amdgcn_mfma_f32_16x16x32_bf16(aH1[s], b1, t, 0, 0, 0);
        }
#pragma unroll
        for (int s = 0; s < 4; ++s) {
            f32x4 t = __builtin_amdgcn_mfma_f32_16x16x32_bf16(aH0[s], e0, zero4, 0, 0, 0);
            d2[s] = __builtin_amdgcn_mfma_f32_16x16x32_bf16(aH1[s], e1, t, 0, 0, 0);
        }
#pragma unroll
        for (int s = 0; s < 4; ++s) {
            const unsigned* cu = (const unsigned*)&cc[s];
#pragma unroll
            for (int r = 0; r < 4; ++r) {
                unsigned u = cu[r];
                g[s][r] += bflo(u) * d[s][r];
                g[s][r] += bfhi(u) * d2[s][r];
            }
        }
    }

    // ---- epilogue: CSR-ordered row writes
    const float alpha = 0.125f;
#pragma unroll
    for (int s = 0; s < 4; ++s) {
#pragma unroll
        for (int r = 0; r < 4; ++r) {
            int el = w * 64 + s * 16 + quad * 4 + r;
            if (eb + el < n_edges)
                erow[(size_t)s_rank[el] * 32 + col] = alpha * g[s][r];
        }
    }
}

// ---------------- gather: wave per atom, lane per feature, sequential rows ------
__global__ __launch_bounds__(256) void gather_kernel(
    const int* __restrict__ off, const float* __restrict__ erow,
    float* __restrict__ out, int n_atoms)
{
    int w = threadIdx.x >> 6, lane = threadIdx.x & 63;
    int a = blockIdx.x * 4 + w;
    if (a >= n_atoms) return;
    int beg = off[a], end = off[a + 1];

    int f = min(lane, 39);
    int u, shi;
    if (f < 8)       { u = f;                 shi = 0; }
    else if (f < 20) { u = 8 + (f - 8) / 3;   shi = 1 + (f - 8) % 3; }
    else             { u = 12 + (f - 20) / 5; shi = 4 + (f - 20) % 5; }

    float val = 0.0f;
    for (int i = beg; i < end; ++i) {
        const float* rp = erow + (size_t)i * 32;
        val += rp[u] * rp[16 + shi];
    }
    if (lane < 40) {
        float c = (float)max(end - beg, 1);
        out[(size_t)a * 40 + lane] = val / c;
    }
}

static inline size_t align256(size_t x) { return (x + 255) & ~(size_t)255; }

extern "C" void kernel_launch(void* const* d_in, const int* in_sizes, int n_in,
                              void* d_out, int out_size, void* d_ws, size_t ws_size,
                              hipStream_t stream)
{
    const float* pos         = (const float*)d_in[0];
    const float* edge_shifts = (const float*)d_in[1];
    const float* cell        = (const float*)d_in[2];
    const float* atom_table  = (const float*)d_in[3];
    const float* fw1 = (const float*)d_in[4];
    const float* fb1 = (const float*)d_in[5];
    const float* fw2 = (const float*)d_in[6];
    const float* fb2 = (const float*)d_in[7];
    const float* fw3 = (const float*)d_in[8];
    const float* fb3 = (const float*)d_in[9];
    const float* gw1 = (const float*)d_in[10];
    const float* gb1 = (const float*)d_in[11];
    const float* gw2 = (const float*)d_in[12];
    const float* gb2 = (const float*)d_in[13];
    const float* gw3 = (const float*)d_in[14];
    const float* gb3 = (const float*)d_in[15];
    const float* gw4 = (const float*)d_in[16];
    const float* gb4 = (const float*)d_in[17];
    const int* A        = (const int*)d_in[18];
    const int* batch    = (const int*)d_in[19];
    const int* edge_src = (const int*)d_in[20];
    const int* edge_dst = (const int*)d_in[21];

    int n_atoms = in_sizes[18];
    int n_edges = in_sizes[20];

    char* w = (char*)d_ws;
    float* Ai = (float*)w;                      w += align256((size_t)n_atoms * 8 * 4);
    int* cnt_i = (int*)w;                       w += align256((size_t)n_atoms * 4);
    int* off = (int*)w;                         w += align256((size_t)(n_atoms + 1) * 4);
    int* cur = (int*)w;                         w += align256((size_t)n_atoms * 4);
    int* rank = (int*)w;                        w += align256((size_t)n_edges * 4);
    unsigned short* W4pk = (unsigned short*)w;  w += align256((size_t)65536 * 2);
    unsigned short* gw1Tp = (unsigned short*)w; w += align256((size_t)2048 * 2);
    unsigned short* gw2T = (unsigned short*)w;  w += align256((size_t)4096 * 2);
    unsigned short* gw3T = (unsigned short*)w;  w += align256((size_t)4096 * 2);
    unsigned short* gb4T2 = (unsigned short*)w; w += align256((size_t)1024 * 2);
    float* erow = (float*)w;                    w += align256((size_t)n_edges * 32 * 4);

    float* out = (float*)d_out;

    hipMemsetAsync(cnt_i, 0, sizeof(int) * (size_t)n_atoms, stream);

    prep_kernel<<<(76800 + 255) / 256, 256, 0, stream>>>(
        gw4, gb4, gw1, gw2, gw3, W4pk, gw1Tp, gw2T, gw3T, gb4T2);

    atoms_kernel<<<(n_atoms + 255) / 256, 256, 0, stream>>>(
        atom_table, A, fw1, fb1, fw2, fb2, fw3, fb3, Ai, n_atoms);

    hist_kernel<<<(n_edges + 255) / 256, 256, 0, stream>>>(edge_dst, cnt_i, n_edges);
    scan_kernel<<<1, 1024, 0, stream>>>(cnt_i, off, cur, n_atoms);
    scatter_kernel<<<(n_edges + 255) / 256, 256, 0, stream>>>(edge_dst, cur, rank, n_edges);

    edge_fused<<<(n_edges + 255) / 256, 256, 0, stream>>>(
        pos, edge_shifts, cell, batch, edge_src, edge_dst, Ai,
        gb1, gb2, gb3, gw1Tp, gw2T, gw3T, W4pk, gb4T2, rank, erow, n_edges);

    gather_kernel<<<(n_atoms + 3) / 4, 256, 0, stream>>>(off, erow, out, n_atoms);
}

// Round 6
// 342.471 us; speedup vs baseline: 5.4776x; 1.1602x over previous
//
#include <hip/hip_runtime.h>
#include <hip/hip_bf16.h>
#include <math.h>

// N=25000, E=400000, S=8, NB=8, RMAX=5, EMB=16, MULS=(8,4,4), DIMS=(1,3,5), WNUM=1024
// g[e,u] = sum_p c[e,p] * ( sum_k h3[e,k] gw4[k, col(p,u)] + gb4[col(p,u)] )
// out[a, f(u,m)] = (1/cnt[a]) * sum_{e: dst=a} alpha * g[e,u] * sh[e, m]

typedef __attribute__((ext_vector_type(8))) short short8;
typedef __attribute__((ext_vector_type(4))) float f32x4;

__device__ __forceinline__ float silu_f(float x) {
    // x * rcp(1+exp(-x)): v_exp + v_rcp, no refined divide (bf16 output tolerates)
    float e = __expf(-x);
    return x * __builtin_amdgcn_rcpf(1.0f + e);
}
__device__ __forceinline__ float silu_exact(float x) { return x / (1.0f + __expf(-x)); }

__device__ __forceinline__ unsigned short bf16r(float f) {
    union { float f; unsigned u; } v; v.f = f;
    return (unsigned short)((v.u + 0x7fffu + ((v.u >> 16) & 1u)) >> 16);
}
__device__ __forceinline__ unsigned pkcvt(float lo, float hi) {
    union { __hip_bfloat162 h; unsigned u; } v;
    v.h = __float22bfloat162_rn(float2{lo, hi});
    return v.u;
}
__device__ __forceinline__ float bflo(unsigned u) {
    union { unsigned u; float f; } v; v.u = u << 16; return v.f;
}
__device__ __forceinline__ float bfhi(unsigned u) {
    union { unsigned u; float f; } v; v.u = u & 0xffff0000u; return v.f;
}
__device__ __forceinline__ int col_pu(int p, int u) {
    return (u < 8) ? (p * 8 + u)
         : (u < 12) ? (512 + p * 4 + (u - 8))
                    : (768 + p * 4 + (u - 12));
}

// ---------------- setup: prep permutes + atom MLP + cnt zero, one launch --------
// blocks [0,300): prep; [300,300+NA_BLK): atoms MLP; [300+NA_BLK, ...): zero cnt
__global__ __launch_bounds__(256) void setup_kernel(
    const float* __restrict__ gw4, const float* __restrict__ gb4,
    const float* __restrict__ gw1, const float* __restrict__ gw2,
    const float* __restrict__ gw3,
    unsigned short* __restrict__ W4pk, unsigned short* __restrict__ gw1Tp,
    unsigned short* __restrict__ gw2T, unsigned short* __restrict__ gw3T,
    unsigned short* __restrict__ gb4T2,
    const float* __restrict__ atom_table, const int* __restrict__ A,
    const float* __restrict__ fw1, const float* __restrict__ fb1,
    const float* __restrict__ fw2, const float* __restrict__ fb2,
    const float* __restrict__ fw3, const float* __restrict__ fb3,
    float* __restrict__ Ai, int* __restrict__ cnt_i, int n_atoms, int na_blk)
{
    int b = blockIdx.x;
    if (b < 300) {
        int idx = b * 256 + threadIdx.x;
        if (idx < 65536) {
            int p = idx >> 10, u = (idx >> 6) & 15, k = idx & 63;
            W4pk[idx] = bf16r(gw4[k * 1024 + col_pu(p, u)]);
        } else if (idx < 67584) {
            int t = idx - 65536; int n = t >> 5, k = t & 31;
            gw1Tp[t] = (k < 8) ? bf16r(gw1[k * 64 + n]) : (unsigned short)0;
        } else if (idx < 71680) {
            int t = idx - 67584; int n = t >> 6, k = t & 63;
            gw2T[t] = bf16r(gw2[k * 64 + n]);
        } else if (idx < 75776) {
            int t = idx - 71680; int n = t >> 6, k = t & 63;
            gw3T[t] = bf16r(gw3[k * 64 + n]);
        } else if (idx < 76800) {
            int t = idx - 75776; int u = t >> 6, p = t & 63;
            gb4T2[t] = bf16r(gb4[col_pu(p, u)]);
        }
        return;
    }
    if (b < 300 + na_blk) {
        int n = (b - 300) * 256 + threadIdx.x;
        if (n >= n_atoms) return;
        const float* at = atom_table + A[n] * 16;

        float h1[64];
#pragma unroll
        for (int t = 0; t < 64; ++t) h1[t] = fb1[t];
#pragma unroll
        for (int k = 0; k < 16; ++k) {
            float x = at[k];
#pragma unroll
            for (int t = 0; t < 64; ++t) h1[t] += x * fw1[k * 64 + t];
        }
#pragma unroll
        for (int t = 0; t < 64; ++t) h1[t] = silu_exact(h1[t]);

        float h2[32];
#pragma unroll
        for (int t = 0; t < 32; ++t) h2[t] = fb2[t];
#pragma unroll
        for (int k = 0; k < 64; ++k) {
            float x = h1[k];
#pragma unroll
            for (int t = 0; t < 32; ++t) h2[t] += x * fw2[k * 32 + t];
        }
#pragma unroll
        for (int t = 0; t < 32; ++t) h2[t] = silu_exact(h2[t]);

        float o[8];
#pragma unroll
        for (int t = 0; t < 8; ++t) o[t] = fb3[t];
#pragma unroll
        for (int k = 0; k < 32; ++k) {
            float x = h2[k];
#pragma unroll
            for (int t = 0; t < 8; ++t) o[t] += x * fw3[k * 8 + t];
        }
#pragma unroll
        for (int t = 0; t < 8; ++t) Ai[n * 8 + t] = o[t];
        return;
    }
    int i = (b - 300 - na_blk) * 256 + threadIdx.x;
    if (i < n_atoms) cnt_i[i] = 0;
}

// ---------------- rank0: per-edge slot within its dst atom (also builds cnt) ----
__global__ __launch_bounds__(256) void rank0_kernel(
    const int* __restrict__ edge_dst, int* __restrict__ cnt,
    int* __restrict__ rank0, int n_edges)
{
    int e = blockIdx.x * 256 + threadIdx.x;
    if (e < n_edges) rank0[e] = atomicAdd(&cnt[edge_dst[e]], 1);
}

// ---------------- scan: off = exclusive prefix sum of cnt ----------------
__global__ __launch_bounds__(1024) void scan_kernel(
    const int* __restrict__ cnt, int* __restrict__ off, int n)
{
    __shared__ int s[1024];
    int tid = threadIdx.x;
    int chunk = (n + 1023) / 1024;
    int start = tid * chunk;
    int end = min(start + chunk, n);
    int sum = 0;
    for (int i = start; i < end; ++i) sum += cnt[i];
    s[tid] = sum;
    __syncthreads();
    for (int d = 1; d < 1024; d <<= 1) {
        int v = (tid >= d) ? s[tid - d] : 0;
        __syncthreads();
        s[tid] += v;
        __syncthreads();
    }
    int run = (tid == 0) ? 0 : s[tid - 1];
    for (int i = start; i < end; ++i) {
        off[i] = run; run += cnt[i];
    }
    if (tid == 1023) off[n] = s[1023];
}

// ---------------- fused edge kernel ----------------
// block = 256 (4 waves), 256 edges/block, 64 edges/wave (4 subtiles of 16).
// All LDS wave-private except the phase A->B union overwrite -> ONE barrier.
__global__ __launch_bounds__(256, 4) void edge_fused(
    const float* __restrict__ pos, const float* __restrict__ edge_shifts,
    const float* __restrict__ cell, const int* __restrict__ batch,
    const int* __restrict__ edge_src, const int* __restrict__ edge_dst,
    const float* __restrict__ Ai,
    const float* __restrict__ gb1, const float* __restrict__ gb2,
    const float* __restrict__ gb3,
    const unsigned short* __restrict__ gw1Tp, const unsigned short* __restrict__ gw2T,
    const unsigned short* __restrict__ gw3T,
    const unsigned short* __restrict__ W4pk, const unsigned short* __restrict__ gb4T2,
    const int* __restrict__ off, const int* __restrict__ rank0,
    float* __restrict__ erow, int n_edges)
{
    // union'd LDS: phase A = s_emb(4K) + s_hh(4x9216); phase B = s_c2(33K)+s_rank(1K)
    __shared__ __align__(16) char smem[40960];
    unsigned short (*s_emb)[8] = (unsigned short(*)[8])smem;

    int tid = threadIdx.x;
    int eb = blockIdx.x * 256;
    int w = tid >> 6, lane = tid & 63, quad = lane >> 4, col = lane & 15;

    unsigned short* s_hhw = (unsigned short*)(smem + 4096 + w * 9216); // [64 rows][72]

    int ec = min(eb + tid, n_edges - 1);
    int src = edge_src[ec], dst = edge_dst[ec];
    int rk = off[dst] + rank0[ec];

    {   // phase 0: geometry -> emb (LDS, wave-private rows) + sh (straight to erow)
        int b = batch[src];
        const float* C = cell + b * 9;
        float es0 = edge_shifts[ec * 3 + 0];
        float es1 = edge_shifts[ec * 3 + 1];
        float es2 = edge_shifts[ec * 3 + 2];
        float vx = pos[dst * 3 + 0] - pos[src * 3 + 0] + es0 * C[0] + es1 * C[3] + es2 * C[6];
        float vy = pos[dst * 3 + 1] - pos[src * 3 + 1] + es0 * C[1] + es1 * C[4] + es2 * C[7];
        float vz = pos[dst * 3 + 2] - pos[src * 3 + 2] + es0 * C[2] + es1 * C[5] + es2 * C[8];
        float r2 = vx * vx + vy * vy + vz * vz + 1e-12f;
        float r = sqrtf(r2);
        float inv = 1.0f / r;
        float x = vx * inv, y = vy * inv, z = vz * inv;

        float xr = fminf(r * 0.2f, 1.0f);
        float cutoff = (r <= 5.0f) ? 2.8284271247461903f : 0.0f;
        float em[8];
#pragma unroll
        for (int k = 0; k < 8; ++k) {
            float d = (xr - (float)k * (1.0f / 7.0f)) * 7.0f;
            em[k] = __expf(-0.5f * d * d) * cutoff;
        }
        *(uint4*)&s_emb[tid][0] = make_uint4(pkcvt(em[0], em[1]), pkcvt(em[2], em[3]),
                                             pkcvt(em[4], em[5]), pkcvt(em[6], em[7]));

        const float s3 = 1.7320508075688772f;
        const float s5 = 2.23606797749979f;
        const float s15 = 3.872983346207417f;
        float* op = erow + (size_t)rk * 32 + 16;
        op[0] = 1.0f;
        op[1] = s3 * x; op[2] = s3 * y; op[3] = s3 * z;
        op[4] = s15 * x * y;
        op[5] = s15 * y * z;
        op[6] = 0.5f * s5 * (2.0f * z * z - x * x - y * y);
        op[7] = s15 * x * z;
        op[8] = 0.5f * s15 * (x * x - y * y);
    }
    // no barrier: s_emb rows [w*64, w*64+64) written and read by wave w only

    // ---- phase A, layer 1: A = emb (k<8 real), B = gw1Tp[n][k32]
#pragma unroll
    for (int s = 0; s < 4; ++s) {
        short8 a = *(const short8*)&s_emb[w * 64 + s * 16 + col][0];
        if (quad != 0) {
            short8 z = {0, 0, 0, 0, 0, 0, 0, 0};
            a = z;
        }
#pragma unroll
        for (int nt = 0; nt < 4; ++nt) {
            int n = nt * 16 + col;
            short8 b = *(const short8*)(gw1Tp + n * 32 + quad * 8);
            float bb = gb1[n];
            f32x4 d = {bb, bb, bb, bb};
            d = __builtin_amdgcn_mfma_f32_16x16x32_bf16(a, b, d, 0, 0, 0);
            unsigned u01 = pkcvt(silu_f(d[0]), silu_f(d[1]));
            unsigned u23 = pkcvt(silu_f(d[2]), silu_f(d[3]));
            unsigned short* bp2 = &s_hhw[(s * 16 + quad * 4) * 72 + n];
            bp2[0]   = (unsigned short)(u01 & 0xffffu);
            bp2[72]  = (unsigned short)(u01 >> 16);
            bp2[144] = (unsigned short)(u23 & 0xffffu);
            bp2[216] = (unsigned short)(u23 >> 16);
        }
    }

    // ---- phase A, layers 2 and 3 (wave-private LDS round trips, no barriers)
#pragma unroll 1
    for (int layer = 0; layer < 2; ++layer) {
        const unsigned short* WT = layer ? gw3T : gw2T;
        const float* gb = layer ? gb3 : gb2;

        short8 a0[4], a1[4];
#pragma unroll
        for (int s = 0; s < 4; ++s) {
            a0[s] = *(const short8*)&s_hhw[(s * 16 + col) * 72 + quad * 8];
            a1[s] = *(const short8*)&s_hhw[(s * 16 + col) * 72 + 32 + quad * 8];
        }

#pragma unroll
        for (int nt = 0; nt < 4; ++nt) {
            int n = nt * 16 + col;
            short8 b0 = *(const short8*)(WT + n * 64 + quad * 8);
            short8 b1 = *(const short8*)(WT + n * 64 + 32 + quad * 8);
            float bb = gb[n];
#pragma unroll
            for (int s = 0; s < 4; ++s) {
                f32x4 d = {bb, bb, bb, bb};
                d = __builtin_amdgcn_mfma_f32_16x16x32_bf16(a0[s], b0, d, 0, 0, 0);
                d = __builtin_amdgcn_mfma_f32_16x16x32_bf16(a1[s], b1, d, 0, 0, 0);
                unsigned u01 = pkcvt(silu_f(d[0]), silu_f(d[1]));
                unsigned u23 = pkcvt(silu_f(d[2]), silu_f(d[3]));
                unsigned short* bp2 = &s_hhw[(s * 16 + quad * 4) * 72 + n];
                bp2[0]   = (unsigned short)(u01 & 0xffffu);
                bp2[72]  = (unsigned short)(u01 >> 16);
                bp2[144] = (unsigned short)(u23 & 0xffffu);
                bp2[216] = (unsigned short)(u23 >> 16);
            }
        }
    }

    // ---- h3 A-frags to registers
    short8 aH0[4], aH1[4];
#pragma unroll
    for (int s = 0; s < 4; ++s) {
        aH0[s] = *(const short8*)&s_hhw[(s * 16 + col) * 72 + quad * 8];
        aH1[s] = *(const short8*)&s_hhw[(s * 16 + col) * 72 + 32 + quad * 8];
    }
    __syncthreads();   // THE barrier: s_c2/s_rank overwrite other waves' s_hh region

    // ---- phase B prep: pair-packed c[pp][e] bf16x2 + rank cache (wave-private cols)
    unsigned* s_c2 = (unsigned*)smem;            // [32][264]
    int* s_rank = (int*)(smem + 33792);
    s_rank[tid] = rk;
    {
        const float4* asp = (const float4*)(Ai + (size_t)src * 8);
        float4 A0 = asp[0], A1 = asp[1];
        const float4* adp = (const float4*)(Ai + (size_t)dst * 8);
        float4 B0 = adp[0], B1 = adp[1];
        float as[8] = {A0.x, A0.y, A0.z, A0.w, A1.x, A1.y, A1.z, A1.w};
        float ad[8] = {B0.x, B0.y, B0.z, B0.w, B1.x, B1.y, B1.z, B1.w};
#pragma unroll
        for (int pp = 0; pp < 32; ++pp) {
            int p = pp * 2;
            float av = as[p >> 3];
            s_c2[pp * 264 + tid] = pkcvt(av * ad[p & 7], av * ad[(p & 7) + 1]);
        }
    }

    // ---- bias GEMM: g = c @ gb4T2^T  (A from s_c2, K=64)
    f32x4 g[4];
    {
        const unsigned short* bbp = gb4T2 + col * 64 + quad * 8;
        short8 b0 = *(const short8*)bbp;
        short8 b1 = *(const short8*)(bbp + 32);
        f32x4 zero4 = {0.0f, 0.0f, 0.0f, 0.0f};
#pragma unroll
        for (int s = 0; s < 4; ++s) {
            int ebase = w * 64 + s * 16 + col;
            union { unsigned u[4]; short8 s8; } ua, ub;
#pragma unroll
            for (int t = 0; t < 4; ++t) ua.u[t] = s_c2[(quad * 4 + t) * 264 + ebase];
#pragma unroll
            for (int t = 0; t < 4; ++t) ub.u[t] = s_c2[(16 + quad * 4 + t) * 264 + ebase];
            f32x4 d = __builtin_amdgcn_mfma_f32_16x16x32_bf16(ua.s8, b0, zero4, 0, 0, 0);
            g[s] = __builtin_amdgcn_mfma_f32_16x16x32_bf16(ub.s8, b1, d, 0, 0, 0);
        }
    }

    // ---- main p-loop (pairs, 1-pair-ahead B prefetch; OOB prefetch lands in gw*T)
    const unsigned short* wb = W4pk + col * 64 + quad * 8;
    const char* cbase = (const char*)s_c2 + w * 256 + quad * 16;
    f32x4 zero4 = {0.0f, 0.0f, 0.0f, 0.0f};

    short8 pb0 = *(const short8*)(wb);
    short8 pb1 = *(const short8*)(wb + 32);
    short8 qb0 = *(const short8*)(wb + 1024);
    short8 qb1 = *(const short8*)(wb + 1056);

#pragma unroll 2
    for (int pp = 0; pp < 32; ++pp) {
        short8 b0 = pb0, b1 = pb1, e0 = qb0, e1 = qb1;
        const unsigned short* nw = wb + (2 * pp + 2) * 1024;
        pb0 = *(const short8*)(nw);
        pb1 = *(const short8*)(nw + 32);
        qb0 = *(const short8*)(nw + 1024);
        qb1 = *(const short8*)(nw + 1056);

        uint4 cc[4];
#pragma unroll
        for (int s = 0; s < 4; ++s)
            cc[s] = *(const uint4*)(cbase + pp * 1056 + s * 64);

        f32x4 d[4], d2[4];
#pragma unroll
        for (int s = 0; s < 4; ++s) {
            f32x4 t = __builtin_amdgcn_mfma_f32_16x16x32_bf16(aH0[s], b0, zero4, 0, 0, 0);
            d[s] = __builtin_amdgcn_mfma_f32_16x16x32_bf16(aH1[s], b1, t, 0, 0, 0);
        }
#pragma unroll
        for (int s = 0; s < 4; ++s) {
            f32x4 t = __builtin_amdgcn_mfma_f32_16x16x32_bf16(aH0[s], e0, zero4, 0, 0, 0);
            d2[s] = __builtin_amdgcn_mfma_f32_16x16x32_bf16(aH1[s], e1, t, 0, 0, 0);
        }
#pragma unroll
        for (int s = 0; s < 4; ++s) {
            const unsigned* cu = (const unsigned*)&cc[s];
#pragma unroll
            for (int r = 0; r < 4; ++r) {
                unsigned u = cu[r];
                g[s][r] += bflo(u) * d[s][r];
                g[s][r] += bfhi(u) * d2[s][r];
            }
        }
    }

    // ---- epilogue: CSR-ordered row writes
    const float alpha = 0.125f;
#pragma unroll
    for (int s = 0; s < 4; ++s) {
#pragma unroll
        for (int r = 0; r < 4; ++r) {
            int el = w * 64 + s * 16 + quad * 4 + r;
            if (eb + el < n_edges)
                erow[(size_t)s_rank[el] * 32 + col] = alpha * g[s][r];
        }
    }
}

// ---------------- gather: wave per atom, lane per feature, sequential rows ------
__global__ __launch_bounds__(256) void gather_kernel(
    const int* __restrict__ off, const float* __restrict__ erow,
    float* __restrict__ out, int n_atoms)
{
    int w = threadIdx.x >> 6, lane = threadIdx.x & 63;
    int a = blockIdx.x * 4 + w;
    if (a >= n_atoms) return;
    int beg = off[a], end = off[a + 1];

    int f = min(lane, 39);
    int u, shi;
    if (f < 8)       { u = f;                 shi = 0; }
    else if (f < 20) { u = 8 + (f - 8) / 3;   shi = 1 + (f - 8) % 3; }
    else             { u = 12 + (f - 20) / 5; shi = 4 + (f - 20) % 5; }

    float val = 0.0f;
    int i = beg;
    for (; i + 1 < end; i += 2) {
        const float* r0 = erow + (size_t)i * 32;
        const float* r1 = erow + (size_t)(i + 1) * 32;
        float v0 = r0[u] * r0[16 + shi];
        float v1 = r1[u] * r1[16 + shi];
        val += v0 + v1;
    }
    if (i < end) {
        const float* r0 = erow + (size_t)i * 32;
        val += r0[u] * r0[16 + shi];
    }
    if (lane < 40) {
        float c = (float)max(end - beg, 1);
        out[(size_t)a * 40 + lane] = val / c;
    }
}

static inline size_t align256(size_t x) { return (x + 255) & ~(size_t)255; }

extern "C" void kernel_launch(void* const* d_in, const int* in_sizes, int n_in,
                              void* d_out, int out_size, void* d_ws, size_t ws_size,
                              hipStream_t stream)
{
    const float* pos         = (const float*)d_in[0];
    const float* edge_shifts = (const float*)d_in[1];
    const float* cell        = (const float*)d_in[2];
    const float* atom_table  = (const float*)d_in[3];
    const float* fw1 = (const float*)d_in[4];
    const float* fb1 = (const float*)d_in[5];
    const float* fw2 = (const float*)d_in[6];
    const float* fb2 = (const float*)d_in[7];
    const float* fw3 = (const float*)d_in[8];
    const float* fb3 = (const float*)d_in[9];
    const float* gw1 = (const float*)d_in[10];
    const float* gb1 = (const float*)d_in[11];
    const float* gw2 = (const float*)d_in[12];
    const float* gb2 = (const float*)d_in[13];
    const float* gw3 = (const float*)d_in[14];
    const float* gb3 = (const float*)d_in[15];
    const float* gw4 = (const float*)d_in[16];
    const float* gb4 = (const float*)d_in[17];
    const int* A        = (const int*)d_in[18];
    const int* batch    = (const int*)d_in[19];
    const int* edge_src = (const int*)d_in[20];
    const int* edge_dst = (const int*)d_in[21];

    int n_atoms = in_sizes[18];
    int n_edges = in_sizes[20];

    char* w = (char*)d_ws;
    float* Ai = (float*)w;                      w += align256((size_t)n_atoms * 8 * 4);
    int* cnt_i = (int*)w;                       w += align256((size_t)n_atoms * 4);
    int* off = (int*)w;                         w += align256((size_t)(n_atoms + 1) * 4);
    int* rank0 = (int*)w;                       w += align256((size_t)n_edges * 4);
    unsigned short* W4pk = (unsigned short*)w;  w += align256((size_t)65536 * 2);
    unsigned short* gw1Tp = (unsigned short*)w; w += align256((size_t)2048 * 2);
    unsigned short* gw2T = (unsigned short*)w;  w += align256((size_t)4096 * 2);
    unsigned short* gw3T = (unsigned short*)w;  w += align256((size_t)4096 * 2);
    unsigned short* gb4T2 = (unsigned short*)w; w += align256((size_t)1024 * 2);
    float* erow = (float*)w;                    w += align256((size_t)n_edges * 32 * 4);

    float* out = (float*)d_out;

    int na_blk = (n_atoms + 255) / 256;
    setup_kernel<<<300 + 2 * na_blk, 256, 0, stream>>>(
        gw4, gb4, gw1, gw2, gw3, W4pk, gw1Tp, gw2T, gw3T, gb4T2,
        atom_table, A, fw1, fb1, fw2, fb2, fw3, fb3, Ai, cnt_i, n_atoms, na_blk);

    rank0_kernel<<<(n_edges + 255) / 256, 256, 0, stream>>>(edge_dst, cnt_i, rank0, n_edges);
    scan_kernel<<<1, 1024, 0, stream>>>(cnt_i, off, n_atoms);

    edge_fused<<<(n_edges + 255) / 256, 256, 0, stream>>>(
        pos, edge_shifts, cell, batch, edge_src, edge_dst, Ai,
        gb1, gb2, gb3, gw1Tp, gw2T, gw3T, W4pk, gb4T2, off, rank0, erow, n_edges);

    gather_kernel<<<(n_atoms + 3) / 4, 256, 0, stream>>>(off, erow, out, n_atoms);
}

// Round 7
// 324.574 us; speedup vs baseline: 5.7796x; 1.0551x over previous
//
#include <hip/hip_runtime.h>
#include <hip/hip_bf16.h>
#include <math.h>

// N=25000, E=400000, S=8, NB=8, RMAX=5, EMB=16, MULS=(8,4,4), DIMS=(1,3,5), WNUM=1024
// g[e,u] = sum_p c[e,p] * ( sum_k h3[e,k] gw4[k, col(p,u)] + gb4[col(p,u)] )
// out[a, f(u,m)] = (1/cnt[a]) * sum_{e: dst=a} alpha * g[e,u] * sh[e, m]

typedef __attribute__((ext_vector_type(8))) short short8;
typedef __attribute__((ext_vector_type(4))) float f32x4;

__device__ __forceinline__ float silu_f(float x) {
    float e = __expf(-x);
    return x * __builtin_amdgcn_rcpf(1.0f + e);
}
__device__ __forceinline__ float silu_exact(float x) { return x / (1.0f + __expf(-x)); }

__device__ __forceinline__ unsigned short bf16r(float f) {
    union { float f; unsigned u; } v; v.f = f;
    return (unsigned short)((v.u + 0x7fffu + ((v.u >> 16) & 1u)) >> 16);
}
__device__ __forceinline__ unsigned pkcvt(float lo, float hi) {
    union { __hip_bfloat162 h; unsigned u; } v;
    v.h = __float22bfloat162_rn(float2{lo, hi});
    return v.u;
}
__device__ __forceinline__ float bflo(unsigned u) {
    union { unsigned u; float f; } v; v.u = u << 16; return v.f;
}
__device__ __forceinline__ float bfhi(unsigned u) {
    union { unsigned u; float f; } v; v.u = u & 0xffff0000u; return v.f;
}
__device__ __forceinline__ int col_pu(int p, int u) {
    return (u < 8) ? (p * 8 + u)
         : (u < 12) ? (512 + p * 4 + (u - 8))
                    : (768 + p * 4 + (u - 12));
}

// ---------------- setup: prep permutes + atom MLP + rank0, one launch ----------
// blocks [0,300): prep; [300,300+na_blk): atoms MLP; rest: rank0 (cnt pre-zeroed
// by hipMemsetAsync, which precedes this kernel in stream order).
__global__ __launch_bounds__(256) void setup_kernel(
    const float* __restrict__ gw4, const float* __restrict__ gb4,
    const float* __restrict__ gw1, const float* __restrict__ gw2,
    const float* __restrict__ gw3,
    unsigned short* __restrict__ W4pk, unsigned short* __restrict__ gw1Tp,
    unsigned short* __restrict__ gw2T, unsigned short* __restrict__ gw3T,
    unsigned short* __restrict__ gb4T2,
    const float* __restrict__ atom_table, const int* __restrict__ A,
    const float* __restrict__ fw1, const float* __restrict__ fb1,
    const float* __restrict__ fw2, const float* __restrict__ fb2,
    const float* __restrict__ fw3, const float* __restrict__ fb3,
    float* __restrict__ Ai, int n_atoms, int na_blk,
    const int* __restrict__ edge_dst, int* __restrict__ cnt_i,
    int* __restrict__ rank0, int n_edges)
{
    int b = blockIdx.x;
    if (b < 300) {
        int idx = b * 256 + threadIdx.x;
        if (idx < 65536) {
            int p = idx >> 10, u = (idx >> 6) & 15, k = idx & 63;
            W4pk[idx] = bf16r(gw4[k * 1024 + col_pu(p, u)]);
        } else if (idx < 67584) {
            int t = idx - 65536; int n = t >> 5, k = t & 31;
            gw1Tp[t] = (k < 8) ? bf16r(gw1[k * 64 + n]) : (unsigned short)0;
        } else if (idx < 71680) {
            int t = idx - 67584; int n = t >> 6, k = t & 63;
            gw2T[t] = bf16r(gw2[k * 64 + n]);
        } else if (idx < 75776) {
            int t = idx - 71680; int n = t >> 6, k = t & 63;
            gw3T[t] = bf16r(gw3[k * 64 + n]);
        } else if (idx < 76800) {
            int t = idx - 75776; int u = t >> 6, p = t & 63;
            gb4T2[t] = bf16r(gb4[col_pu(p, u)]);
        }
        return;
    }
    if (b < 300 + na_blk) {
        int n = (b - 300) * 256 + threadIdx.x;
        if (n >= n_atoms) return;
        const float* at = atom_table + A[n] * 16;

        float h1[64];
#pragma unroll
        for (int t = 0; t < 64; ++t) h1[t] = fb1[t];
#pragma unroll
        for (int k = 0; k < 16; ++k) {
            float x = at[k];
#pragma unroll
            for (int t = 0; t < 64; ++t) h1[t] += x * fw1[k * 64 + t];
        }
#pragma unroll
        for (int t = 0; t < 64; ++t) h1[t] = silu_exact(h1[t]);

        float h2[32];
#pragma unroll
        for (int t = 0; t < 32; ++t) h2[t] = fb2[t];
#pragma unroll
        for (int k = 0; k < 64; ++k) {
            float x = h1[k];
#pragma unroll
            for (int t = 0; t < 32; ++t) h2[t] += x * fw2[k * 32 + t];
        }
#pragma unroll
        for (int t = 0; t < 32; ++t) h2[t] = silu_exact(h2[t]);

        float o[8];
#pragma unroll
        for (int t = 0; t < 8; ++t) o[t] = fb3[t];
#pragma unroll
        for (int k = 0; k < 32; ++k) {
            float x = h2[k];
#pragma unroll
            for (int t = 0; t < 8; ++t) o[t] += x * fw3[k * 8 + t];
        }
#pragma unroll
        for (int t = 0; t < 8; ++t) Ai[n * 8 + t] = o[t];
        return;
    }
    int e = (b - 300 - na_blk) * 256 + threadIdx.x;
    if (e < n_edges) rank0[e] = atomicAdd(&cnt_i[edge_dst[e]], 1);
}

// ---------------- scan: off = exclusive prefix sum of cnt ----------------
__global__ __launch_bounds__(1024) void scan_kernel(
    const int* __restrict__ cnt, int* __restrict__ off, int n)
{
    __shared__ int s[1024];
    int tid = threadIdx.x;
    int chunk = (n + 1023) / 1024;
    int start = tid * chunk;
    int end = min(start + chunk, n);
    int sum = 0;
    for (int i = start; i < end; ++i) sum += cnt[i];
    s[tid] = sum;
    __syncthreads();
    for (int d = 1; d < 1024; d <<= 1) {
        int v = (tid >= d) ? s[tid - d] : 0;
        __syncthreads();
        s[tid] += v;
        __syncthreads();
    }
    int run = (tid == 0) ? 0 : s[tid - 1];
    for (int i = start; i < end; ++i) {
        off[i] = run; run += cnt[i];
    }
    if (tid == 1023) off[n] = s[1023];
}

// ---------------- fused edge kernel ----------------
// block = 256 (4 waves), 256 edges/block, 64 edges/wave (4 subtiles of 16).
// LDS 36864 B -> 4 blocks/CU. One barrier (phase A->B union overwrite).
__global__ __launch_bounds__(256, 4) void edge_fused(
    const float* __restrict__ pos, const float* __restrict__ edge_shifts,
    const float* __restrict__ cell, const int* __restrict__ batch,
    const int* __restrict__ edge_src, const int* __restrict__ edge_dst,
    const float* __restrict__ Ai,
    const float* __restrict__ gb1, const float* __restrict__ gb2,
    const float* __restrict__ gb3,
    const unsigned short* __restrict__ gw1Tp, const unsigned short* __restrict__ gw2T,
    const unsigned short* __restrict__ gw3T,
    const unsigned short* __restrict__ W4pk, const unsigned short* __restrict__ gb4T2,
    const int* __restrict__ off, const int* __restrict__ rank0,
    float* __restrict__ erow, int n_edges)
{
    // phase A: s_hh 4 waves x [64][72] shorts = 36864; phase B: s_c2 33792 + rank 1024
    __shared__ __align__(16) char smem[36864];

    int tid = threadIdx.x;
    int eb = blockIdx.x * 256;
    int w = tid >> 6, lane = tid & 63, quad = lane >> 4, col = lane & 15;

    unsigned short* s_hhw = (unsigned short*)(smem + w * 9216); // [64 rows][72]

    int ec = min(eb + tid, n_edges - 1);
    int src = edge_src[ec], dst = edge_dst[ec];
    int rk = off[dst] + rank0[ec];

    uint4 em4;
    {   // phase 0: geometry -> emb (regs) + sh (straight to erow, float4)
        int b = batch[src];
        const float* C = cell + b * 9;
        float es0 = edge_shifts[ec * 3 + 0];
        float es1 = edge_shifts[ec * 3 + 1];
        float es2 = edge_shifts[ec * 3 + 2];
        float vx = pos[dst * 3 + 0] - pos[src * 3 + 0] + es0 * C[0] + es1 * C[3] + es2 * C[6];
        float vy = pos[dst * 3 + 1] - pos[src * 3 + 1] + es0 * C[1] + es1 * C[4] + es2 * C[7];
        float vz = pos[dst * 3 + 2] - pos[src * 3 + 2] + es0 * C[2] + es1 * C[5] + es2 * C[8];
        float r2 = vx * vx + vy * vy + vz * vz + 1e-12f;
        float r = sqrtf(r2);
        float inv = 1.0f / r;
        float x = vx * inv, y = vy * inv, z = vz * inv;

        float xr = fminf(r * 0.2f, 1.0f);
        float cutoff = (r <= 5.0f) ? 2.8284271247461903f : 0.0f;
        float em[8];
#pragma unroll
        for (int k = 0; k < 8; ++k) {
            float d = (xr - (float)k * (1.0f / 7.0f)) * 7.0f;
            em[k] = __expf(-0.5f * d * d) * cutoff;
        }
        em4 = make_uint4(pkcvt(em[0], em[1]), pkcvt(em[2], em[3]),
                         pkcvt(em[4], em[5]), pkcvt(em[6], em[7]));

        const float s3 = 1.7320508075688772f;
        const float s5 = 2.23606797749979f;
        const float s15 = 3.872983346207417f;
        float* op = erow + (size_t)rk * 32 + 16;
        *(float4*)op = float4{1.0f, s3 * x, s3 * y, s3 * z};
        *(float4*)(op + 4) = float4{s15 * x * y, s15 * y * z,
                                    0.5f * s5 * (2.0f * z * z - x * x - y * y),
                                    s15 * x * z};
        op[8] = 0.5f * s15 * (x * x - y * y);
    }

    // ---- phase A, layer 1: A-frag via shfl (quad 0 holds k<8, rest zero)
#pragma unroll
    for (int s = 0; s < 4; ++s) {
        int sl = w * 64 + s * 16 + col;   // absolute thread id owning this edge
        union { unsigned u[4]; short8 s8; } ua;
        ua.u[0] = (unsigned)__shfl((int)em4.x, sl & 63, 64);
        ua.u[1] = (unsigned)__shfl((int)em4.y, sl & 63, 64);
        ua.u[2] = (unsigned)__shfl((int)em4.z, sl & 63, 64);
        ua.u[3] = (unsigned)__shfl((int)em4.w, sl & 63, 64);
        short8 a = ua.s8;
        if (quad != 0) {
            short8 z = {0, 0, 0, 0, 0, 0, 0, 0};
            a = z;
        }
#pragma unroll
        for (int nt = 0; nt < 4; ++nt) {
            int n = nt * 16 + col;
            short8 b = *(const short8*)(gw1Tp + n * 32 + quad * 8);
            float bb = gb1[n];
            f32x4 d = {bb, bb, bb, bb};
            d = __builtin_amdgcn_mfma_f32_16x16x32_bf16(a, b, d, 0, 0, 0);
            unsigned u01 = pkcvt(silu_f(d[0]), silu_f(d[1]));
            unsigned u23 = pkcvt(silu_f(d[2]), silu_f(d[3]));
            unsigned short* bp2 = &s_hhw[(s * 16 + quad * 4) * 72 + n];
            bp2[0]   = (unsigned short)(u01 & 0xffffu);
            bp2[72]  = (unsigned short)(u01 >> 16);
            bp2[144] = (unsigned short)(u23 & 0xffffu);
            bp2[216] = (unsigned short)(u23 >> 16);
        }
    }

    // ---- phase A, layers 2 and 3 (wave-private LDS round trips)
#pragma unroll 1
    for (int layer = 0; layer < 2; ++layer) {
        const unsigned short* WT = layer ? gw3T : gw2T;
        const float* gb = layer ? gb3 : gb2;

        short8 a0[4], a1[4];
#pragma unroll
        for (int s = 0; s < 4; ++s) {
            a0[s] = *(const short8*)&s_hhw[(s * 16 + col) * 72 + quad * 8];
            a1[s] = *(const short8*)&s_hhw[(s * 16 + col) * 72 + 32 + quad * 8];
        }

#pragma unroll
        for (int nt = 0; nt < 4; ++nt) {
            int n = nt * 16 + col;
            short8 b0 = *(const short8*)(WT + n * 64 + quad * 8);
            short8 b1 = *(const short8*)(WT + n * 64 + 32 + quad * 8);
            float bb = gb[n];
#pragma unroll
            for (int s = 0; s < 4; ++s) {
                f32x4 d = {bb, bb, bb, bb};
                d = __builtin_amdgcn_mfma_f32_16x16x32_bf16(a0[s], b0, d, 0, 0, 0);
                d = __builtin_amdgcn_mfma_f32_16x16x32_bf16(a1[s], b1, d, 0, 0, 0);
                unsigned u01 = pkcvt(silu_f(d[0]), silu_f(d[1]));
                unsigned u23 = pkcvt(silu_f(d[2]), silu_f(d[3]));
                unsigned short* bp2 = &s_hhw[(s * 16 + quad * 4) * 72 + n];
                bp2[0]   = (unsigned short)(u01 & 0xffffu);
                bp2[72]  = (unsigned short)(u01 >> 16);
                bp2[144] = (unsigned short)(u23 & 0xffffu);
                bp2[216] = (unsigned short)(u23 >> 16);
            }
        }
    }

    // ---- h3 A-frags to registers
    short8 aH0[4], aH1[4];
#pragma unroll
    for (int s = 0; s < 4; ++s) {
        aH0[s] = *(const short8*)&s_hhw[(s * 16 + col) * 72 + quad * 8];
        aH1[s] = *(const short8*)&s_hhw[(s * 16 + col) * 72 + 32 + quad * 8];
    }
    __syncthreads();   // THE barrier: s_c2/s_rank overwrite other waves' s_hh

    // ---- phase B prep: pair-packed c[pp][e] bf16x2 + rank cache
    unsigned* s_c2 = (unsigned*)smem;            // [32][264]
    int* s_rank = (int*)(smem + 33792);
    s_rank[tid] = rk;
    {
        const float4* asp = (const float4*)(Ai + (size_t)src * 8);
        float4 A0 = asp[0], A1 = asp[1];
        const float4* adp = (const float4*)(Ai + (size_t)dst * 8);
        float4 B0 = adp[0], B1 = adp[1];
        float as[8] = {A0.x, A0.y, A0.z, A0.w, A1.x, A1.y, A1.z, A1.w};
        float ad[8] = {B0.x, B0.y, B0.z, B0.w, B1.x, B1.y, B1.z, B1.w};
#pragma unroll
        for (int pp = 0; pp < 32; ++pp) {
            int p = pp * 2;
            float av = as[p >> 3];
            s_c2[pp * 264 + tid] = pkcvt(av * ad[p & 7], av * ad[(p & 7) + 1]);
        }
    }

    // ---- bias GEMM: g = c @ gb4T2^T  (A from s_c2, K=64)
    f32x4 g[4];
    {
        const unsigned short* bbp = gb4T2 + col * 64 + quad * 8;
        short8 b0 = *(const short8*)bbp;
        short8 b1 = *(const short8*)(bbp + 32);
        f32x4 zero4 = {0.0f, 0.0f, 0.0f, 0.0f};
#pragma unroll
        for (int s = 0; s < 4; ++s) {
            int ebase = w * 64 + s * 16 + col;
            union { unsigned u[4]; short8 s8; } ua, ub;
#pragma unroll
            for (int t = 0; t < 4; ++t) ua.u[t] = s_c2[(quad * 4 + t) * 264 + ebase];
#pragma unroll
            for (int t = 0; t < 4; ++t) ub.u[t] = s_c2[(16 + quad * 4 + t) * 264 + ebase];
            f32x4 d = __builtin_amdgcn_mfma_f32_16x16x32_bf16(ua.s8, b0, zero4, 0, 0, 0);
            g[s] = __builtin_amdgcn_mfma_f32_16x16x32_bf16(ub.s8, b1, d, 0, 0, 0);
        }
    }

    // ---- main p-loop: 2-pair-deep B prefetch (8 KB in flight)
    const unsigned short* wb = W4pk + col * 64 + quad * 8;
    const char* cbase = (const char*)s_c2 + w * 256 + quad * 16;
    f32x4 zero4 = {0.0f, 0.0f, 0.0f, 0.0f};

    short8 Pb0[2], Pb1[2], Qb0[2], Qb1[2];
    Pb0[0] = *(const short8*)(wb);
    Pb1[0] = *(const short8*)(wb + 32);
    Qb0[0] = *(const short8*)(wb + 1024);
    Qb1[0] = *(const short8*)(wb + 1056);
    Pb0[1] = *(const short8*)(wb + 2048);
    Pb1[1] = *(const short8*)(wb + 2080);
    Qb0[1] = *(const short8*)(wb + 3072);
    Qb1[1] = *(const short8*)(wb + 3104);

#pragma unroll 2
    for (int pp = 0; pp < 32; ++pp) {
        int slot = pp & 1;
        short8 b0 = Pb0[slot], b1 = Pb1[slot], e0 = Qb0[slot], e1 = Qb1[slot];
        // prefetch pair pp+2 (rows up to 67 overrun into gw1Tp/gw2T — harmless)
        const unsigned short* nw = wb + (2 * pp + 4) * 1024;
        Pb0[slot] = *(const short8*)(nw);
        Pb1[slot] = *(const short8*)(nw + 32);
        Qb0[slot] = *(const short8*)(nw + 1024);
        Qb1[slot] = *(const short8*)(nw + 1056);

        uint4 cc[4];
#pragma unroll
        for (int s = 0; s < 4; ++s)
            cc[s] = *(const uint4*)(cbase + pp * 1056 + s * 64);

        f32x4 d[4], d2[4];
#pragma unroll
        for (int s = 0; s < 4; ++s) {
            f32x4 t = __builtin_amdgcn_mfma_f32_16x16x32_bf16(aH0[s], b0, zero4, 0, 0, 0);
            d[s] = __builtin_amdgcn_mfma_f32_16x16x32_bf16(aH1[s], b1, t, 0, 0, 0);
        }
#pragma unroll
        for (int s = 0; s < 4; ++s) {
            f32x4 t = __builtin_amdgcn_mfma_f32_16x16x32_bf16(aH0[s], e0, zero4, 0, 0, 0);
            d2[s] = __builtin_amdgcn_mfma_f32_16x16x32_bf16(aH1[s], e1, t, 0, 0, 0);
        }
#pragma unroll
        for (int s = 0; s < 4; ++s) {
            const unsigned* cu = (const unsigned*)&cc[s];
#pragma unroll
            for (int r = 0; r < 4; ++r) {
                unsigned u = cu[r];
                g[s][r] += bflo(u) * d[s][r];
                g[s][r] += bfhi(u) * d2[s][r];
            }
        }
    }

    // ---- epilogue: CSR-ordered row writes
    const float alpha = 0.125f;
#pragma unroll
    for (int s = 0; s < 4; ++s) {
#pragma unroll
        for (int r = 0; r < 4; ++r) {
            int el = w * 64 + s * 16 + quad * 4 + r;
            if (eb + el < n_edges)
                erow[(size_t)s_rank[el] * 32 + col] = alpha * g[s][r];
        }
    }
}

// ---------------- gather: wave per atom, LDS-staged coalesced rows ----------
__global__ __launch_bounds__(256) void gather_kernel(
    const int* __restrict__ off, const float* __restrict__ erow,
    float* __restrict__ out, int n_atoms)
{
    __shared__ float s_rows[4][8][34];   // stride 34 dwords: <=2-way on f2 writes
    int w = threadIdx.x >> 6, lane = threadIdx.x & 63;
    int a = blockIdx.x * 4 + w;
    if (a >= n_atoms) return;
    int beg = off[a], end = off[a + 1];

    int f = min(lane, 39);
    int u, shi;
    if (f < 8)       { u = f;                 shi = 0; }
    else if (f < 20) { u = 8 + (f - 8) / 3;   shi = 1 + (f - 8) % 3; }
    else             { u = 12 + (f - 20) / 5; shi = 4 + (f - 20) % 5; }

    int rsub = lane >> 3, csub = lane & 7;   // lane covers row rsub, dwords csub*4..+4
    float val = 0.0f;
    for (int i = beg; i < end; i += 8) {
        int nr = min(8, end - i);
        int ri = i + rsub;
        float4 v = (ri < end) ? *(const float4*)(erow + (size_t)ri * 32 + csub * 4)
                              : float4{0.0f, 0.0f, 0.0f, 0.0f};
        *(float2*)&s_rows[w][rsub][csub * 4]     = float2{v.x, v.y};
        *(float2*)&s_rows[w][rsub][csub * 4 + 2] = float2{v.z, v.w};
        // wave-private LDS slice: compiler-inserted waitcnt suffices, no barrier
#pragma unroll
        for (int j = 0; j < 8; ++j) {
            float prod = s_rows[w][j][u] * s_rows[w][j][16 + shi];
            val += (j < nr) ? prod : 0.0f;
        }
    }
    if (lane < 40) {
        float c = (float)max(end - beg, 1);
        out[(size_t)a * 40 + lane] = val / c;
    }
}

static inline size_t align256(size_t x) { return (x + 255) & ~(size_t)255; }

extern "C" void kernel_launch(void* const* d_in, const int* in_sizes, int n_in,
                              void* d_out, int out_size, void* d_ws, size_t ws_size,
                              hipStream_t stream)
{
    const float* pos         = (const float*)d_in[0];
    const float* edge_shifts = (const float*)d_in[1];
    const float* cell        = (const float*)d_in[2];
    const float* atom_table  = (const float*)d_in[3];
    const float* fw1 = (const float*)d_in[4];
    const float* fb1 = (const float*)d_in[5];
    const float* fw2 = (const float*)d_in[6];
    const float* fb2 = (const float*)d_in[7];
    const float* fw3 = (const float*)d_in[8];
    const float* fb3 = (const float*)d_in[9];
    const float* gw1 = (const float*)d_in[10];
    const float* gb1 = (const float*)d_in[11];
    const float* gw2 = (const float*)d_in[12];
    const float* gb2 = (const float*)d_in[13];
    const float* gw3 = (const float*)d_in[14];
    const float* gb3 = (const float*)d_in[15];
    const float* gw4 = (const float*)d_in[16];
    const float* gb4 = (const float*)d_in[17];
    const int* A        = (const int*)d_in[18];
    const int* batch    = (const int*)d_in[19];
    const int* edge_src = (const int*)d_in[20];
    const int* edge_dst = (const int*)d_in[21];

    int n_atoms = in_sizes[18];
    int n_edges = in_sizes[20];

    char* w = (char*)d_ws;
    float* Ai = (float*)w;                      w += align256((size_t)n_atoms * 8 * 4);
    int* cnt_i = (int*)w;                       w += align256((size_t)n_atoms * 4);
    int* off = (int*)w;                         w += align256((size_t)(n_atoms + 1) * 4);
    int* rank0 = (int*)w;                       w += align256((size_t)n_edges * 4);
    unsigned short* W4pk = (unsigned short*)w;  w += align256((size_t)65536 * 2);
    unsigned short* gw1Tp = (unsigned short*)w; w += align256((size_t)2048 * 2);
    unsigned short* gw2T = (unsigned short*)w;  w += align256((size_t)4096 * 2);
    unsigned short* gw3T = (unsigned short*)w;  w += align256((size_t)4096 * 2);
    unsigned short* gb4T2 = (unsigned short*)w; w += align256((size_t)1024 * 2);
    float* erow = (float*)w;                    w += align256((size_t)n_edges * 32 * 4);

    float* out = (float*)d_out;

    hipMemsetAsync(cnt_i, 0, sizeof(int) * (size_t)n_atoms, stream);

    int na_blk = (n_atoms + 255) / 256;
    int e_blk = (n_edges + 255) / 256;
    setup_kernel<<<300 + na_blk + e_blk, 256, 0, stream>>>(
        gw4, gb4, gw1, gw2, gw3, W4pk, gw1Tp, gw2T, gw3T, gb4T2,
        atom_table, A, fw1, fb1, fw2, fb2, fw3, fb3, Ai, n_atoms, na_blk,
        edge_dst, cnt_i, rank0, n_edges);

    scan_kernel<<<1, 1024, 0, stream>>>(cnt_i, off, n_atoms);

    edge_fused<<<(n_edges + 255) / 256, 256, 0, stream>>>(
        pos, edge_shifts, cell, batch, edge_src, edge_dst, Ai,
        gb1, gb2, gb3, gw1Tp, gw2T, gw3T, W4pk, gb4T2, off, rank0, erow, n_edges);

    gather_kernel<<<(n_atoms + 3) / 4, 256, 0, stream>>>(off, erow, out, n_atoms);
}

// Round 8
// 320.002 us; speedup vs baseline: 5.8622x; 1.0143x over previous
//
#include <hip/hip_runtime.h>
#include <hip/hip_bf16.h>
#include <math.h>

// N=25000, E=400000, S=8, NB=8, RMAX=5, EMB=16, MULS=(8,4,4), DIMS=(1,3,5), WNUM=1024
// g[e,u] = sum_p c[e,p] * ( sum_k h3[e,k] gw4[k, col(p,u)] + gb4[col(p,u)] )
// out[a, f(u,m)] = (1/cnt[a]) * sum_{e: dst=a} alpha * g[e,u] * sh[e, m]

typedef __attribute__((ext_vector_type(8))) short short8;
typedef __attribute__((ext_vector_type(4))) float f32x4;

#define EROW 28   // floats per edge row: g[16] + sh[9] + pad (112 B, 16-aligned)

__device__ __forceinline__ float silu_f(float x) {
    float e = __expf(-x);
    return x * __builtin_amdgcn_rcpf(1.0f + e);
}
__device__ __forceinline__ float silu_exact(float x) { return x / (1.0f + __expf(-x)); }

__device__ __forceinline__ unsigned short bf16r(float f) {
    union { float f; unsigned u; } v; v.f = f;
    return (unsigned short)((v.u + 0x7fffu + ((v.u >> 16) & 1u)) >> 16);
}
__device__ __forceinline__ unsigned pkcvt(float lo, float hi) {
    union { __hip_bfloat162 h; unsigned u; } v;
    v.h = __float22bfloat162_rn(float2{lo, hi});
    return v.u;
}
__device__ __forceinline__ float bflo(unsigned u) {
    union { unsigned u; float f; } v; v.u = u << 16; return v.f;
}
__device__ __forceinline__ float bfhi(unsigned u) {
    union { unsigned u; float f; } v; v.u = u & 0xffff0000u; return v.f;
}

// ---------------- setup: prep permutes + atom MLP + rank0, one launch ----------
// blocks [0,300): prep (COALESCED reads, scattered writes);
// [300,300+na_blk): atoms MLP; rest: rank0 (cnt pre-zeroed by hipMemsetAsync).
__global__ __launch_bounds__(256) void setup_kernel(
    const float* __restrict__ gw4, const float* __restrict__ gb4,
    const float* __restrict__ gw1, const float* __restrict__ gw2,
    const float* __restrict__ gw3,
    unsigned short* __restrict__ W4pk, unsigned short* __restrict__ gw1Tp,
    unsigned short* __restrict__ gw2T, unsigned short* __restrict__ gw3T,
    unsigned short* __restrict__ gb4T2,
    const float* __restrict__ atom_table, const int* __restrict__ A,
    const float* __restrict__ fw1, const float* __restrict__ fb1,
    const float* __restrict__ fw2, const float* __restrict__ fb2,
    const float* __restrict__ fw3, const float* __restrict__ fb3,
    float* __restrict__ Ai, int n_atoms, int na_blk,
    const int* __restrict__ edge_dst, int* __restrict__ cnt_i,
    int* __restrict__ rank0, int n_edges)
{
    int b = blockIdx.x;
    if (b < 300) {
        int idx = b * 256 + threadIdx.x;
        if (idx < 65536) {
            // read gw4 linearly (coalesced), scatter-write W4pk[p][u][k]
            int k = idx >> 10, col = idx & 1023;
            int p, u;
            if (col < 512)      { p = col >> 3;          u = col & 7; }
            else if (col < 768) { p = (col - 512) >> 2;  u = 8 + ((col - 512) & 3); }
            else                { p = (col - 768) >> 2;  u = 12 + ((col - 768) & 3); }
            W4pk[p * 1024 + u * 64 + k] = bf16r(gw4[idx]);
        } else if (idx < 67584) {
            int t = idx - 65536; int n = t >> 5, k = t & 31;
            gw1Tp[t] = (k < 8) ? bf16r(gw1[k * 64 + n]) : (unsigned short)0;
        } else if (idx < 71680) {
            int t = idx - 67584; int n = t >> 6, k = t & 63;
            gw2T[t] = bf16r(gw2[k * 64 + n]);
        } else if (idx < 75776) {
            int t = idx - 71680; int n = t >> 6, k = t & 63;
            gw3T[t] = bf16r(gw3[k * 64 + n]);
        } else if (idx < 76800) {
            // gb4T2[u][p]  (coalesced read of gb4 impossible at this size; tiny)
            int t = idx - 75776; int u = t >> 6, p = t & 63;
            int colb = (u < 8) ? (p * 8 + u)
                     : (u < 12) ? (512 + p * 4 + (u - 8))
                                : (768 + p * 4 + (u - 12));
            gb4T2[t] = bf16r(gb4[colb]);
        }
        return;
    }
    if (b < 300 + na_blk) {
        int n = (b - 300) * 256 + threadIdx.x;
        if (n >= n_atoms) return;
        const float* at = atom_table + A[n] * 16;

        float h1[64];
#pragma unroll
        for (int t = 0; t < 64; ++t) h1[t] = fb1[t];
#pragma unroll
        for (int k = 0; k < 16; ++k) {
            float x = at[k];
#pragma unroll
            for (int t = 0; t < 64; ++t) h1[t] += x * fw1[k * 64 + t];
        }
#pragma unroll
        for (int t = 0; t < 64; ++t) h1[t] = silu_exact(h1[t]);

        float h2[32];
#pragma unroll
        for (int t = 0; t < 32; ++t) h2[t] = fb2[t];
#pragma unroll
        for (int k = 0; k < 64; ++k) {
            float x = h1[k];
#pragma unroll
            for (int t = 0; t < 32; ++t) h2[t] += x * fw2[k * 32 + t];
        }
#pragma unroll
        for (int t = 0; t < 32; ++t) h2[t] = silu_exact(h2[t]);

        float o[8];
#pragma unroll
        for (int t = 0; t < 8; ++t) o[t] = fb3[t];
#pragma unroll
        for (int k = 0; k < 32; ++k) {
            float x = h2[k];
#pragma unroll
            for (int t = 0; t < 8; ++t) o[t] += x * fw3[k * 8 + t];
        }
#pragma unroll
        for (int t = 0; t < 8; ++t) Ai[n * 8 + t] = o[t];
        return;
    }
    int e = (b - 300 - na_blk) * 256 + threadIdx.x;
    if (e < n_edges) rank0[e] = atomicAdd(&cnt_i[edge_dst[e]], 1);
}

// ---------------- scan: off = exclusive prefix sum of cnt ----------------
__global__ __launch_bounds__(1024) void scan_kernel(
    const int* __restrict__ cnt, int* __restrict__ off, int n)
{
    __shared__ int s[1024];
    int tid = threadIdx.x;
    int chunk = (n + 1023) / 1024;
    int start = tid * chunk;
    int end = min(start + chunk, n);
    int sum = 0;
    for (int i = start; i < end; ++i) sum += cnt[i];
    s[tid] = sum;
    __syncthreads();
    for (int d = 1; d < 1024; d <<= 1) {
        int v = (tid >= d) ? s[tid - d] : 0;
        __syncthreads();
        s[tid] += v;
        __syncthreads();
    }
    int run = (tid == 0) ? 0 : s[tid - 1];
    for (int i = start; i < end; ++i) {
        off[i] = run; run += cnt[i];
    }
    if (tid == 1023) off[n] = s[1023];
}

// ---------------- fused edge kernel: ONE WAVE per workgroup ----------------
// 64 edges/wave (4 subtiles of 16). LDS 8448 B -> up to 16 WGs/CU, ZERO barriers
// (all LDS wave-private; within-wave DS ops execute in order).
__global__ __launch_bounds__(64, 4) void edge_fused(
    const float* __restrict__ pos, const float* __restrict__ edge_shifts,
    const float* __restrict__ cell, const int* __restrict__ batch,
    const int* __restrict__ edge_src, const int* __restrict__ edge_dst,
    const float* __restrict__ Ai,
    const float* __restrict__ gb1, const float* __restrict__ gb2,
    const float* __restrict__ gb3,
    const unsigned short* __restrict__ gw1Tp, const unsigned short* __restrict__ gw2T,
    const unsigned short* __restrict__ gw3T,
    const unsigned short* __restrict__ W4pk, const unsigned short* __restrict__ gb4T2,
    const int* __restrict__ off, const int* __restrict__ rank0,
    float* __restrict__ erow, int n_edges)
{
    // union: phase A h-buffer [64 rows][66] shorts = 8448 B;
    //        phase B c-buffer [32 pairs][66] u32  = 8448 B
    __shared__ __align__(16) char smem[8448];
    unsigned short* s_hh = (unsigned short*)smem;
    unsigned* s_c2 = (unsigned*)smem;

    int lane = threadIdx.x;
    int eb = blockIdx.x * 64;
    int quad = lane >> 4, col = lane & 15;

    int ec = min(eb + lane, n_edges - 1);
    int src = edge_src[ec], dst = edge_dst[ec];
    int rk = off[dst] + rank0[ec];

    uint4 em4;
    {   // phase 0: geometry -> emb (regs) + sh (straight to erow, float4)
        int b = batch[src];
        const float* C = cell + b * 9;
        float es0 = edge_shifts[ec * 3 + 0];
        float es1 = edge_shifts[ec * 3 + 1];
        float es2 = edge_shifts[ec * 3 + 2];
        float vx = pos[dst * 3 + 0] - pos[src * 3 + 0] + es0 * C[0] + es1 * C[3] + es2 * C[6];
        float vy = pos[dst * 3 + 1] - pos[src * 3 + 1] + es0 * C[1] + es1 * C[4] + es2 * C[7];
        float vz = pos[dst * 3 + 2] - pos[src * 3 + 2] + es0 * C[2] + es1 * C[5] + es2 * C[8];
        float r2 = vx * vx + vy * vy + vz * vz + 1e-12f;
        float r = sqrtf(r2);
        float inv = 1.0f / r;
        float x = vx * inv, y = vy * inv, z = vz * inv;

        float xr = fminf(r * 0.2f, 1.0f);
        float cutoff = (r <= 5.0f) ? 2.8284271247461903f : 0.0f;
        float em[8];
#pragma unroll
        for (int k = 0; k < 8; ++k) {
            float d = (xr - (float)k * (1.0f / 7.0f)) * 7.0f;
            em[k] = __expf(-0.5f * d * d) * cutoff;
        }
        em4 = make_uint4(pkcvt(em[0], em[1]), pkcvt(em[2], em[3]),
                         pkcvt(em[4], em[5]), pkcvt(em[6], em[7]));

        const float s3 = 1.7320508075688772f;
        const float s5 = 2.23606797749979f;
        const float s15 = 3.872983346207417f;
        float* op = erow + (size_t)rk * EROW + 16;
        *(float4*)op = float4{1.0f, s3 * x, s3 * y, s3 * z};
        *(float4*)(op + 4) = float4{s15 * x * y, s15 * y * z,
                                    0.5f * s5 * (2.0f * z * z - x * x - y * y),
                                    s15 * x * z};
        op[8] = 0.5f * s15 * (x * x - y * y);
    }

    // ---- phase A, layer 1: A-frag via shfl (quad 0 holds k<8, rest zero)
#pragma unroll
    for (int s = 0; s < 4; ++s) {
        int sl = s * 16 + col;   // lane owning this edge
        union { unsigned u[4]; short8 s8; } ua;
        ua.u[0] = (unsigned)__shfl((int)em4.x, sl, 64);
        ua.u[1] = (unsigned)__shfl((int)em4.y, sl, 64);
        ua.u[2] = (unsigned)__shfl((int)em4.z, sl, 64);
        ua.u[3] = (unsigned)__shfl((int)em4.w, sl, 64);
        short8 a = ua.s8;
        if (quad != 0) {
            short8 z = {0, 0, 0, 0, 0, 0, 0, 0};
            a = z;
        }
#pragma unroll
        for (int nt = 0; nt < 4; ++nt) {
            int n = nt * 16 + col;
            short8 b = *(const short8*)(gw1Tp + n * 32 + quad * 8);
            float bb = gb1[n];
            f32x4 d = {bb, bb, bb, bb};
            d = __builtin_amdgcn_mfma_f32_16x16x32_bf16(a, b, d, 0, 0, 0);
            unsigned u01 = pkcvt(silu_f(d[0]), silu_f(d[1]));
            unsigned u23 = pkcvt(silu_f(d[2]), silu_f(d[3]));
            unsigned short* bp2 = &s_hh[(s * 16 + quad * 4) * 66 + n];
            bp2[0]   = (unsigned short)(u01 & 0xffffu);
            bp2[66]  = (unsigned short)(u01 >> 16);
            bp2[132] = (unsigned short)(u23 & 0xffffu);
            bp2[198] = (unsigned short)(u23 >> 16);
        }
    }

    // ---- phase A, layers 2 and 3 (wave-private LDS round trips)
#pragma unroll 1
    for (int layer = 0; layer < 2; ++layer) {
        const unsigned short* WT = layer ? gw3T : gw2T;
        const float* gb = layer ? gb3 : gb2;

        short8 a0[4], a1[4];
#pragma unroll
        for (int s = 0; s < 4; ++s) {
            a0[s] = *(const short8*)&s_hh[(s * 16 + col) * 66 + quad * 8];
            a1[s] = *(const short8*)&s_hh[(s * 16 + col) * 66 + 32 + quad * 8];
        }

#pragma unroll
        for (int nt = 0; nt < 4; ++nt) {
            int n = nt * 16 + col;
            short8 b0 = *(const short8*)(WT + n * 64 + quad * 8);
            short8 b1 = *(const short8*)(WT + n * 64 + 32 + quad * 8);
            float bb = gb[n];
#pragma unroll
            for (int s = 0; s < 4; ++s) {
                f32x4 d = {bb, bb, bb, bb};
                d = __builtin_amdgcn_mfma_f32_16x16x32_bf16(a0[s], b0, d, 0, 0, 0);
                d = __builtin_amdgcn_mfma_f32_16x16x32_bf16(a1[s], b1, d, 0, 0, 0);
                unsigned u01 = pkcvt(silu_f(d[0]), silu_f(d[1]));
                unsigned u23 = pkcvt(silu_f(d[2]), silu_f(d[3]));
                unsigned short* bp2 = &s_hh[(s * 16 + quad * 4) * 66 + n];
                bp2[0]   = (unsigned short)(u01 & 0xffffu);
                bp2[66]  = (unsigned short)(u01 >> 16);
                bp2[132] = (unsigned short)(u23 & 0xffffu);
                bp2[198] = (unsigned short)(u23 >> 16);
            }
        }
    }

    // ---- h3 A-frags to registers (in-order DS pipe: reads precede c overwrites)
    short8 aH0[4], aH1[4];
#pragma unroll
    for (int s = 0; s < 4; ++s) {
        aH0[s] = *(const short8*)&s_hh[(s * 16 + col) * 66 + quad * 8];
        aH1[s] = *(const short8*)&s_hh[(s * 16 + col) * 66 + 32 + quad * 8];
    }

    // ---- phase B prep: pair-packed c[pp][e] bf16x2 (overwrites h-buffer)
    {
        const float4* asp = (const float4*)(Ai + (size_t)src * 8);
        float4 A0 = asp[0], A1 = asp[1];
        const float4* adp = (const float4*)(Ai + (size_t)dst * 8);
        float4 B0 = adp[0], B1 = adp[1];
        float as[8] = {A0.x, A0.y, A0.z, A0.w, A1.x, A1.y, A1.z, A1.w};
        float ad[8] = {B0.x, B0.y, B0.z, B0.w, B1.x, B1.y, B1.z, B1.w};
#pragma unroll
        for (int pp = 0; pp < 32; ++pp) {
            int p = pp * 2;
            float av = as[p >> 3];
            s_c2[pp * 66 + lane] = pkcvt(av * ad[p & 7], av * ad[(p & 7) + 1]);
        }
    }

    // ---- bias GEMM: g = c @ gb4T2^T  (A from s_c2, K=64)
    f32x4 g[4];
    {
        const unsigned short* bbp = gb4T2 + col * 64 + quad * 8;
        short8 b0 = *(const short8*)bbp;
        short8 b1 = *(const short8*)(bbp + 32);
        f32x4 zero4 = {0.0f, 0.0f, 0.0f, 0.0f};
#pragma unroll
        for (int s = 0; s < 4; ++s) {
            int ebase = s * 16 + col;
            union { unsigned u[4]; short8 s8; } ua, ub;
#pragma unroll
            for (int t = 0; t < 4; ++t) ua.u[t] = s_c2[(quad * 4 + t) * 66 + ebase];
#pragma unroll
            for (int t = 0; t < 4; ++t) ub.u[t] = s_c2[(16 + quad * 4 + t) * 66 + ebase];
            f32x4 d = __builtin_amdgcn_mfma_f32_16x16x32_bf16(ua.s8, b0, zero4, 0, 0, 0);
            g[s] = __builtin_amdgcn_mfma_f32_16x16x32_bf16(ub.s8, b1, d, 0, 0, 0);
        }
    }

    // ---- main p-loop: 2-pair-deep B prefetch (8 KB in flight)
    const unsigned short* wb = W4pk + col * 64 + quad * 8;
    const char* cbase = (const char*)s_c2 + quad * 16;
    f32x4 zero4 = {0.0f, 0.0f, 0.0f, 0.0f};

    short8 Pb0[2], Pb1[2], Qb0[2], Qb1[2];
    Pb0[0] = *(const short8*)(wb);
    Pb1[0] = *(const short8*)(wb + 32);
    Qb0[0] = *(const short8*)(wb + 1024);
    Qb1[0] = *(const short8*)(wb + 1056);
    Pb0[1] = *(const short8*)(wb + 2048);
    Pb1[1] = *(const short8*)(wb + 2080);
    Qb0[1] = *(const short8*)(wb + 3072);
    Qb1[1] = *(const short8*)(wb + 3104);

#pragma unroll 2
    for (int pp = 0; pp < 32; ++pp) {
        int slot = pp & 1;
        short8 b0 = Pb0[slot], b1 = Pb1[slot], e0 = Qb0[slot], e1 = Qb1[slot];
        // prefetch pair pp+2 (tail overruns into gw1Tp/gw2T — harmless)
        const unsigned short* nw = wb + (2 * pp + 4) * 1024;
        Pb0[slot] = *(const short8*)(nw);
        Pb1[slot] = *(const short8*)(nw + 32);
        Qb0[slot] = *(const short8*)(nw + 1024);
        Qb1[slot] = *(const short8*)(nw + 1056);

        uint4 cc[4];
#pragma unroll
        for (int s = 0; s < 4; ++s)
            cc[s] = *(const uint4*)(cbase + pp * 264 + s * 64);

        f32x4 d[4], d2[4];
#pragma unroll
        for (int s = 0; s < 4; ++s) {
            f32x4 t = __builtin_amdgcn_mfma_f32_16x16x32_bf16(aH0[s], b0, zero4, 0, 0, 0);
            d[s] = __builtin_amdgcn_mfma_f32_16x16x32_bf16(aH1[s], b1, t, 0, 0, 0);
        }
#pragma unroll
        for (int s = 0; s < 4; ++s) {
            f32x4 t = __builtin_amdgcn_mfma_f32_16x16x32_bf16(aH0[s], e0, zero4, 0, 0, 0);
            d2[s] = __builtin_amdgcn_mfma_f32_16x16x32_bf16(aH1[s], e1, t, 0, 0, 0);
        }
#pragma unroll
        for (int s = 0; s < 4; ++s) {
            const unsigned* cu = (const unsigned*)&cc[s];
#pragma unroll
            for (int r = 0; r < 4; ++r) {
                unsigned u = cu[r];
                g[s][r] += bflo(u) * d[s][r];
                g[s][r] += bfhi(u) * d2[s][r];
            }
        }
    }

    // ---- epilogue: CSR-ordered row writes, rank via shfl
    const float alpha = 0.125f;
#pragma unroll
    for (int s = 0; s < 4; ++s) {
#pragma unroll
        for (int r = 0; r < 4; ++r) {
            int el = s * 16 + quad * 4 + r;
            int rkv = __shfl(rk, el, 64);
            if (eb + el < n_edges)
                erow[(size_t)rkv * EROW + col] = alpha * g[s][r];
        }
    }
}

// ---------------- gather: wave per atom, LDS-staged coalesced rows ----------
__global__ __launch_bounds__(256) void gather_kernel(
    const int* __restrict__ off, const float* __restrict__ erow,
    float* __restrict__ out, int n_atoms)
{
    __shared__ float s_rows[4][8][30];
    int w = threadIdx.x >> 6, lane = threadIdx.x & 63;
    int a = blockIdx.x * 4 + w;
    if (a >= n_atoms) return;
    int beg = off[a], end = off[a + 1];

    int f = min(lane, 39);
    int u, shi;
    if (f < 8)       { u = f;                 shi = 0; }
    else if (f < 20) { u = 8 + (f - 8) / 3;   shi = 1 + (f - 8) % 3; }
    else             { u = 12 + (f - 20) / 5; shi = 4 + (f - 20) % 5; }

    int rsub = lane >> 3, csub = lane & 7;   // lane stages row rsub, dwords csub*4..+4
    float val = 0.0f;
    for (int i = beg; i < end; i += 8) {
        int nr = min(8, end - i);
        int ri = i + rsub;
        if (csub < 7) {   // 28 dwords per row
            float4 v = (ri < end) ? *(const float4*)(erow + (size_t)ri * EROW + csub * 4)
                                  : float4{0.0f, 0.0f, 0.0f, 0.0f};
            *(float2*)&s_rows[w][rsub][csub * 4]     = float2{v.x, v.y};
            *(float2*)&s_rows[w][rsub][csub * 4 + 2] = float2{v.z, v.w};
        }
        // wave-private LDS slice: compiler waitcnt suffices, no barrier
#pragma unroll
        for (int j = 0; j < 8; ++j) {
            float prod = s_rows[w][j][u] * s_rows[w][j][16 + shi];
            val += (j < nr) ? prod : 0.0f;
        }
    }
    if (lane < 40) {
        float c = (float)max(end - beg, 1);
        out[(size_t)a * 40 + lane] = val / c;
    }
}

static inline size_t align256(size_t x) { return (x + 255) & ~(size_t)255; }

extern "C" void kernel_launch(void* const* d_in, const int* in_sizes, int n_in,
                              void* d_out, int out_size, void* d_ws, size_t ws_size,
                              hipStream_t stream)
{
    const float* pos         = (const float*)d_in[0];
    const float* edge_shifts = (const float*)d_in[1];
    const float* cell        = (const float*)d_in[2];
    const float* atom_table  = (const float*)d_in[3];
    const float* fw1 = (const float*)d_in[4];
    const float* fb1 = (const float*)d_in[5];
    const float* fw2 = (const float*)d_in[6];
    const float* fb2 = (const float*)d_in[7];
    const float* fw3 = (const float*)d_in[8];
    const float* fb3 = (const float*)d_in[9];
    const float* gw1 = (const float*)d_in[10];
    const float* gb1 = (const float*)d_in[11];
    const float* gw2 = (const float*)d_in[12];
    const float* gb2 = (const float*)d_in[13];
    const float* gw3 = (const float*)d_in[14];
    const float* gb3 = (const float*)d_in[15];
    const float* gw4 = (const float*)d_in[16];
    const float* gb4 = (const float*)d_in[17];
    const int* A        = (const int*)d_in[18];
    const int* batch    = (const int*)d_in[19];
    const int* edge_src = (const int*)d_in[20];
    const int* edge_dst = (const int*)d_in[21];

    int n_atoms = in_sizes[18];
    int n_edges = in_sizes[20];

    char* w = (char*)d_ws;
    float* Ai = (float*)w;                      w += align256((size_t)n_atoms * 8 * 4);
    int* cnt_i = (int*)w;                       w += align256((size_t)n_atoms * 4);
    int* off = (int*)w;                         w += align256((size_t)(n_atoms + 1) * 4);
    int* rank0 = (int*)w;                       w += align256((size_t)n_edges * 4);
    unsigned short* W4pk = (unsigned short*)w;  w += align256((size_t)65536 * 2);
    unsigned short* gw1Tp = (unsigned short*)w; w += align256((size_t)2048 * 2);
    unsigned short* gw2T = (unsigned short*)w;  w += align256((size_t)4096 * 2);
    unsigned short* gw3T = (unsigned short*)w;  w += align256((size_t)4096 * 2);
    unsigned short* gb4T2 = (unsigned short*)w; w += align256((size_t)1024 * 2);
    float* erow = (float*)w;                    w += align256((size_t)n_edges * EROW * 4);

    float* out = (float*)d_out;

    hipMemsetAsync(cnt_i, 0, sizeof(int) * (size_t)n_atoms, stream);

    int na_blk = (n_atoms + 255) / 256;
    int e_blk = (n_edges + 255) / 256;
    setup_kernel<<<300 + na_blk + e_blk, 256, 0, stream>>>(
        gw4, gb4, gw1, gw2, gw3, W4pk, gw1Tp, gw2T, gw3T, gb4T2,
        atom_table, A, fw1, fb1, fw2, fb2, fw3, fb3, Ai, n_atoms, na_blk,
        edge_dst, cnt_i, rank0, n_edges);

    scan_kernel<<<1, 1024, 0, stream>>>(cnt_i, off, n_atoms);

    edge_fused<<<(n_edges + 63) / 64, 64, 0, stream>>>(
        pos, edge_shifts, cell, batch, edge_src, edge_dst, Ai,
        gb1, gb2, gb3, gw1Tp, gw2T, gw3T, W4pk, gb4T2, off, rank0, erow, n_edges);

    gather_kernel<<<(n_atoms + 3) / 4, 256, 0, stream>>>(off, erow, out, n_atoms);
}